// Round 9
// baseline (481.038 us; speedup 1.0000x reference)
//
#include <hip/hip_runtime.h>
#include <hip/hip_bf16.h>

#define NN 4096
#define DMODEL 512
#define ODIM 256
#define NHEAD 4
#define DKH 64
#define NKW 64  // NN/64 mask words per row

typedef __attribute__((ext_vector_type(8))) short short8;
typedef __attribute__((ext_vector_type(4))) short short4v;
typedef __attribute__((ext_vector_type(8))) __bf16 bf16x8;
typedef __attribute__((ext_vector_type(4))) float f32x4;
typedef __attribute__((ext_vector_type(4))) unsigned int u32x4;

__device__ __forceinline__ short f2bf(float f) {
    unsigned u = __builtin_bit_cast(unsigned, f);
    u += 0x7fffu + ((u >> 16) & 1u);   // RNE (no NaN in this data)
    return (short)(u >> 16);
}
__device__ __forceinline__ float bf2f(short s) {
    unsigned u = ((unsigned)(unsigned short)s) << 16;
    return __builtin_bit_cast(float, u);
}
__device__ __forceinline__ unsigned pack2bf(float a, float b) {
    return (unsigned)(unsigned short)f2bf(a) | ((unsigned)(unsigned short)f2bf(b) << 16);
}
__device__ __forceinline__ f32x4 mfma16(short8 a, short8 b, f32x4 c) {
    return __builtin_amdgcn_mfma_f32_16x16x32_bf16(
        __builtin_bit_cast(bf16x8, a), __builtin_bit_cast(bf16x8, b), c, 0, 0, 0);
}

// ---------------- mask int32 -> bitmask (1 = keep) ----------------
__global__ __launch_bounds__(256) void pack_mask_k(const int* __restrict__ mask,
                                                   unsigned long long* __restrict__ bits) {
    int tid = blockIdx.x * 256 + threadIdx.x;
    int wid = tid >> 6;
    int lane = tid & 63;
    int v = __builtin_nontemporal_load(mask + (size_t)wid * 64 + lane);
    unsigned long long b = __ballot(v != 0);
    if (lane == 0) bits[wid] = b;
}

// ---------------- 4 projections: Y = X @ W^T + b, bf16 out ----------------
// z=0: q (query,Wq) -> qh [h][n][64], PRE-SCALED by 1/8 (exact in bf16)
// z=1: k -> kh [h][n][64]; z=2: qv -> qvT [h][64][n]; z=3: kv -> kvT [h][64][n]
__global__ __launch_bounds__(256) void proj_k(
    const float* __restrict__ Xq, const float* __restrict__ Xk,
    const float* __restrict__ Wq, const float* __restrict__ bq,
    const float* __restrict__ Wk, const float* __restrict__ bk,
    const float* __restrict__ Wqv, const float* __restrict__ bqv,
    const float* __restrict__ Wkv, const float* __restrict__ bkv,
    short* __restrict__ qh, short* __restrict__ kh,
    short* __restrict__ qvT, short* __restrict__ kvT) {
    int z = blockIdx.z;
    const float *X, *W, *B;
    short* out;
    int tr;
    float postscale = 1.f;
    switch (z) {
        case 0: X = Xq; W = Wq;  B = bq;  out = qh;  tr = 0; postscale = 0.125f; break;
        case 1: X = Xk; W = Wk;  B = bk;  out = kh;  tr = 0; break;
        case 2: X = Xq; W = Wqv; B = bqv; out = qvT; tr = 1; break;
        default: X = Xk; W = Wkv; B = bkv; out = kvT; tr = 1; break;
    }
    int lane = threadIdx.x & 63, w = threadIdx.x >> 6;
    int lr = lane & 15, lg = lane >> 4;
    int m0 = blockIdx.x * 64 + (w >> 1) * 32;
    int n0 = blockIdx.y * 64 + (w & 1) * 32;

    f32x4 acc[2][2] = {};
    for (int kk = 0; kk < DMODEL; kk += 32) {
        short8 a[2], b[2];
#pragma unroll
        for (int i = 0; i < 2; i++) {
            const float* pa = X + (size_t)(m0 + i * 16 + lr) * DMODEL + kk + lg * 8;
            const float* pb = W + (size_t)(n0 + i * 16 + lr) * DMODEL + kk + lg * 8;
            float4 a0 = *(const float4*)pa;
            float4 a1 = *(const float4*)(pa + 4);
            float4 b0 = *(const float4*)pb;
            float4 b1 = *(const float4*)(pb + 4);
            a[i][0] = f2bf(a0.x); a[i][1] = f2bf(a0.y); a[i][2] = f2bf(a0.z); a[i][3] = f2bf(a0.w);
            a[i][4] = f2bf(a1.x); a[i][5] = f2bf(a1.y); a[i][6] = f2bf(a1.z); a[i][7] = f2bf(a1.w);
            b[i][0] = f2bf(b0.x); b[i][1] = f2bf(b0.y); b[i][2] = f2bf(b0.z); b[i][3] = f2bf(b0.w);
            b[i][4] = f2bf(b1.x); b[i][5] = f2bf(b1.y); b[i][6] = f2bf(b1.z); b[i][7] = f2bf(b1.w);
        }
#pragma unroll
        for (int i = 0; i < 2; i++)
#pragma unroll
            for (int j = 0; j < 2; j++) acc[i][j] = mfma16(a[i], b[j], acc[i][j]);
    }
#pragma unroll
    for (int i = 0; i < 2; i++)
#pragma unroll
        for (int j = 0; j < 2; j++) {
            int col = n0 + j * 16 + lr;
            float bv = B[col];
            int hh = col >> 6, dk = col & 63;
#pragma unroll
            for (int r = 0; r < 4; r++) {
                int row = m0 + i * 16 + lg * 4 + r;
                short s = f2bf((acc[i][j][r] + bv) * postscale);
                if (!tr) out[((size_t)hh * NN + row) * DKH + dk] = s;
                else     out[((size_t)hh * DKH + dk) * NN + row] = s;
            }
        }
}

// ---------------- QK pass 1: masked exp-sum -> linv. No stores. ----------------
// Per (16-q strip, head), 8 waves; wave w sweeps k-tiles [w*8, w*8+8).
__global__ __launch_bounds__(512) void attn_sum_k(
    const short* __restrict__ qh, const short* __restrict__ kh,
    const unsigned long long* __restrict__ bits,
    float* __restrict__ linv_ws) {
    int h = blockIdx.y;
    int q0 = blockIdx.x * 16;
    int tid = threadIdx.x, lane = tid & 63, w = tid >> 6;
    int lr = lane & 15, lg = lane >> 4;

    __shared__ float sl[8][16];

    const short* khh = kh + (size_t)h * NN * DKH;
    const unsigned long long* brow = bits + (size_t)(q0 + lr) * NKW;

    short8 bq[2];
#pragma unroll
    for (int kk = 0; kk < 2; kk++)
        bq[kk] = *(const short8*)(qh + ((size_t)h * NN + q0 + lr) * DKH + kk * 32 + lg * 8);

    float lrun = 0.f;
    for (int t = 0; t < 8; t++) {
        int kt = w * 8 + t;
        f32x4 s[4] = {};
#pragma unroll
        for (int fj = 0; fj < 4; fj++)
#pragma unroll
            for (int kk = 0; kk < 2; kk++) {
                short8 a = *(const short8*)(khh + (size_t)(kt * 64 + fj * 16 + lr) * DKH + kk * 32 + lg * 8);
                s[fj] = mfma16(a, bq[kk], s[fj]);
            }
        unsigned long long mw = brow[kt] >> (lg * 4);
#pragma unroll
        for (int fj = 0; fj < 4; fj++)
#pragma unroll
            for (int r = 0; r < 4; r++) {
                bool keep = (mw >> (fj * 16 + r)) & 1ull;
                if (keep) lrun += __expf(s[fj][r]);
            }
    }
    lrun += __shfl_xor(lrun, 16);
    lrun += __shfl_xor(lrun, 32);
    if (lg == 0) sl[w][lr] = lrun;
    __syncthreads();
    if (tid < 16) {
        float l = 0.f;
#pragma unroll
        for (int w2 = 0; w2 < 8; w2++) l += sl[w2][tid];
        linv_ws[(size_t)h * NN + q0 + tid] = l > 0.f ? 1.f / l : 0.f;
    }
}

// ---------------- QK pass 2: p write (f32, normalized) + x1 ----------------
// Per (16-q strip, head), 8 waves; wave w sweeps k-tiles [w*8, w*8+8).
__global__ __launch_bounds__(512) void attn_px1_k(
    const short* __restrict__ qh, const short* __restrict__ kh, const short* __restrict__ kvT,
    const unsigned long long* __restrict__ bits, const float* __restrict__ linv_ws,
    float* __restrict__ x1_out, float* __restrict__ p_out) {
    int h = blockIdx.y;
    int q0 = blockIdx.x * 16;
    int tid = threadIdx.x, lane = tid & 63, w = tid >> 6;
    int lr = lane & 15, lg = lane >> 4;

    __shared__ float smemf[4608];                       // 18 KB union
    short (*plds)[16][72] = (short (*)[16][72])smemf;   // [8][16][72] bf16
    float (*xbuf)[64][17] = (float (*)[64][17])smemf;   // [4][64][17] f32

    const short* khh = kh + (size_t)h * NN * DKH;
    const unsigned long long* brow = bits + (size_t)(q0 + lr) * NKW;
    float linv = linv_ws[(size_t)h * NN + q0 + lr];

    short8 bq[2];
#pragma unroll
    for (int kk = 0; kk < 2; kk++)
        bq[kk] = *(const short8*)(qh + ((size_t)h * NN + q0 + lr) * DKH + kk * 32 + lg * 8);

    f32x4 acc1[4] = {};
    float* prow = p_out + ((size_t)h * NN + q0 + lr) * NN;
    for (int t = 0; t < 8; t++) {
        int kt = w * 8 + t;
        f32x4 s[4] = {};
#pragma unroll
        for (int fj = 0; fj < 4; fj++)
#pragma unroll
            for (int kk = 0; kk < 2; kk++) {
                short8 a = *(const short8*)(khh + (size_t)(kt * 64 + fj * 16 + lr) * DKH + kk * 32 + lg * 8);
                s[fj] = mfma16(a, bq[kk], s[fj]);
            }
        unsigned long long mw = brow[kt] >> (lg * 4);
#pragma unroll
        for (int fj = 0; fj < 4; fj++) {
            float4 pv;
            short4v pb;
#pragma unroll
            for (int r = 0; r < 4; r++) {
                bool keep = (mw >> (fj * 16 + r)) & 1ull;
                float p = keep ? __expf(s[fj][r]) * linv : 0.f;
                (&pv.x)[r] = p;
                pb[r] = f2bf(p);
            }
            *(float4*)(prow + kt * 64 + fj * 16 + lg * 4) = pv;
            *(short4v*)&plds[w][lr][fj * 16 + lg * 4] = pb;
        }
        // x1 += p @ kv (wave-private LDS strip; in-wave lgkmcnt ordering)
#pragma unroll
        for (int kk = 0; kk < 2; kk++) {
            short8 a1 = *(const short8*)&plds[w][lr][kk * 32 + lg * 8];
#pragma unroll
            for (int fd = 0; fd < 4; fd++) {
                short8 bv = *(const short8*)(kvT + ((size_t)h * DKH + fd * 16 + lr) * NN + kt * 64 + kk * 32 + lg * 8);
                acc1[fd] = mfma16(a1, bv, acc1[fd]);
            }
        }
    }
    // ---- two-phase staggered cross-wave x1 reduce (reuses plds memory) ----
    __syncthreads();
    if (w >= 4) {
#pragma unroll
        for (int fd = 0; fd < 4; fd++)
#pragma unroll
            for (int r = 0; r < 4; r++) xbuf[w - 4][lane][fd * 4 + r] = acc1[fd][r];
    }
    __syncthreads();
    if (w < 4) {
#pragma unroll
        for (int fd = 0; fd < 4; fd++)
#pragma unroll
            for (int r = 0; r < 4; r++) acc1[fd][r] += xbuf[w][lane][fd * 4 + r];
    }
    __syncthreads();
    if (w >= 1 && w < 4) {
#pragma unroll
        for (int fd = 0; fd < 4; fd++)
#pragma unroll
            for (int r = 0; r < 4; r++) xbuf[w - 1][lane][fd * 4 + r] = acc1[fd][r];
    }
    __syncthreads();
    if (w == 0) {
#pragma unroll
        for (int fd = 0; fd < 4; fd++)
#pragma unroll
            for (int r = 0; r < 4; r++) {
                float v = acc1[fd][r] + xbuf[0][lane][fd * 4 + r] + xbuf[1][lane][fd * 4 + r] +
                          xbuf[2][lane][fd * 4 + r];
                v = v > 0.f ? v : (__expf(v) - 1.f);
                x1_out[(size_t)(q0 + lg * 4 + r) * ODIM + h * DKH + fd * 16 + lr] = v;
            }
    }
}

// scale qv by linv along q: qvS[h][d][q] = qvT[h][d][q] * linv[h][q]
__global__ __launch_bounds__(256) void scale_qv_k(const short* __restrict__ qvT,
                                                  const float* __restrict__ linv,
                                                  short* __restrict__ qvS) {
    int idx = blockIdx.x * 256 + threadIdx.x;   // 131072 threads, short8 each
    int q8 = idx & 511;
    int dh = idx >> 9;                          // h*64 + d
    int h = dh >> 6;
    short8 v = *(const short8*)(qvT + (size_t)dh * NN + q8 * 8);
    const float* lp = linv + (size_t)h * NN + q8 * 8;
    float4 l0 = *(const float4*)lp;
    float4 l1 = *(const float4*)(lp + 4);
    short8 o;
    o[0] = f2bf(bf2f(v[0]) * l0.x); o[1] = f2bf(bf2f(v[1]) * l0.y);
    o[2] = f2bf(bf2f(v[2]) * l0.z); o[3] = f2bf(bf2f(v[3]) * l0.w);
    o[4] = f2bf(bf2f(v[4]) * l1.x); o[5] = f2bf(bf2f(v[5]) * l1.y);
    o[6] = f2bf(bf2f(v[6]) * l1.z); o[7] = f2bf(bf2f(v[7]) * l1.w);
    *(short8*)(qvS + (size_t)dh * NN + q8 * 8) = o;
}

// ---------------- QK pass 3: x2part = P~^T @ qvS (recompute, no pbuf) ----------------
// Block (bx = 64-key tile, h, z = q-quarter), 8 waves = (fk 0..3 key-group,
// sh 0..1 q-half). S^T via mfma(Q,K): lane holds key row (key = k0+fk*16+lr),
// q values at (qhalf, lg*4+r). In-register transpose (8 shfl + 4 select) forms
// the bf16x8 A-frag [key row][32 q]; x2 += mfma(A, qvS-frag).
__global__ __launch_bounds__(512) void px2c_k(
    const short* __restrict__ qh, const short* __restrict__ kh,
    const short* __restrict__ qvS, const unsigned long long* __restrict__ bits,
    float* __restrict__ x2part) {
    int bx = blockIdx.x, h = blockIdx.y, z = blockIdx.z;
    int tid = threadIdx.x, lane = tid & 63, w = tid >> 6;
    int fk = w & 3, sh = w >> 2;
    int lr = lane & 15, lg = lane >> 4;
    int k0 = bx * 64;

    __shared__ float red[4][64][17];

    const short* khh = kh + (size_t)h * NN * DKH;
    const short* qhh = qh + (size_t)h * NN * DKH;
    const short* qvh = qvS + (size_t)h * DKH * NN;

    short8 bk2[2];
#pragma unroll
    for (int kk = 0; kk < 2; kk++)
        bk2[kk] = *(const short8*)(khh + (size_t)(k0 + fk * 16 + lr) * DKH + kk * 32 + lg * 8);

    f32x4 acc[4] = {};
    int qbase = z * 1024 + sh * 512;
    int kbit = fk * 16 + lr;
    int sA = lr + (((2 * lg) & 3) << 4);
    int sB = lr + (((2 * lg + 1) & 3) << 4);
    bool lowhalf = lg < 2;

    for (int it = 0; it < 16; it++) {
        int qq = qbase + it * 32;
        f32x4 slo = {}, shi = {};
#pragma unroll
        for (int kk = 0; kk < 2; kk++) {
            short8 alo = *(const short8*)(qhh + (size_t)(qq + lr) * DKH + kk * 32 + lg * 8);
            slo = mfma16(alo, bk2[kk], slo);
        }
#pragma unroll
        for (int kk = 0; kk < 2; kk++) {
            short8 ahi = *(const short8*)(qhh + (size_t)(qq + 16 + lr) * DKH + kk * 32 + lg * 8);
            shi = mfma16(ahi, bk2[kk], shi);
        }
        // masked exp (lane holds S^T[key=k0+fk*16+lr][q])
        float el[4], eh[4];
#pragma unroll
        for (int r = 0; r < 4; r++) {
            unsigned long long mwl = bits[(size_t)(qq + lg * 4 + r) * NKW + bx];
            el[r] = ((mwl >> kbit) & 1ull) ? __expf(slo[r]) : 0.f;
            unsigned long long mwh = bits[(size_t)(qq + 16 + lg * 4 + r) * NKW + bx];
            eh[r] = ((mwh >> kbit) & 1ull) ? __expf(shi[r]) : 0.f;
        }
        unsigned lo_w0 = pack2bf(el[0], el[1]), lo_w1 = pack2bf(el[2], el[3]);
        unsigned hi_w0 = pack2bf(eh[0], eh[1]), hi_w1 = pack2bf(eh[2], eh[3]);
        // transpose: lane (lr,lg) gathers A[key=own row][q = lg*8 .. lg*8+7]
        unsigned a0l = (unsigned)__shfl((int)lo_w0, sA);
        unsigned a0h = (unsigned)__shfl((int)hi_w0, sA);
        unsigned a1l = (unsigned)__shfl((int)lo_w1, sA);
        unsigned a1h = (unsigned)__shfl((int)hi_w1, sA);
        unsigned a2l = (unsigned)__shfl((int)lo_w0, sB);
        unsigned a2h = (unsigned)__shfl((int)hi_w0, sB);
        unsigned a3l = (unsigned)__shfl((int)lo_w1, sB);
        unsigned a3h = (unsigned)__shfl((int)hi_w1, sB);
        u32x4 aw;
        aw.x = lowhalf ? a0l : a0h;
        aw.y = lowhalf ? a1l : a1h;
        aw.z = lowhalf ? a2l : a2h;
        aw.w = lowhalf ? a3l : a3h;
        short8 af = __builtin_bit_cast(short8, aw);
#pragma unroll
        for (int fd = 0; fd < 4; fd++) {
            short8 bv = *(const short8*)(qvh + (size_t)(fd * 16 + lr) * NN + qq + lg * 8);
            acc[fd] = mfma16(af, bv, acc[fd]);
        }
    }
    // ---- combine sh halves ----
    if (sh == 1) {
#pragma unroll
        for (int fd = 0; fd < 4; fd++)
#pragma unroll
            for (int r = 0; r < 4; r++) red[fk][lane][fd * 4 + r] = acc[fd][r];
    }
    __syncthreads();
    if (sh == 0) {
        float* xp = x2part + (size_t)z * NN * ODIM;
#pragma unroll
        for (int fd = 0; fd < 4; fd++)
#pragma unroll
            for (int r = 0; r < 4; r++) {
                float v = acc[fd][r] + red[fk][lane][fd * 4 + r];
                xp[(size_t)(k0 + fk * 16 + lg * 4 + r) * ODIM + h * DKH + fd * 16 + lr] = v;
            }
    }
}

// combine: x2 = ELU(part0 + part1 + part2 + part3)
__global__ __launch_bounds__(256) void combine_x2_k(const float* __restrict__ x2part,
                                                    float* __restrict__ x2_out) {
    int idx = blockIdx.x * 256 + threadIdx.x;   // 262144 threads, float4 each
    size_t i = (size_t)idx * 4;
    const size_t stride = (size_t)NN * ODIM;
    float4 a = *(const float4*)(x2part + i);
    float4 b = *(const float4*)(x2part + stride + i);
    float4 c = *(const float4*)(x2part + 2 * stride + i);
    float4 d = *(const float4*)(x2part + 3 * stride + i);
    float4 o;
    o.x = a.x + b.x + c.x + d.x;
    o.y = a.y + b.y + c.y + d.y;
    o.z = a.z + b.z + c.z + d.z;
    o.w = a.w + b.w + c.w + d.w;
    o.x = o.x > 0.f ? o.x : (__expf(o.x) - 1.f);
    o.y = o.y > 0.f ? o.y : (__expf(o.y) - 1.f);
    o.z = o.z > 0.f ? o.z : (__expf(o.z) - 1.f);
    o.w = o.w > 0.f ? o.w : (__expf(o.w) - 1.f);
    *(float4*)(x2_out + i) = o;
}

extern "C" void kernel_launch(void* const* d_in, const int* in_sizes, int n_in,
                              void* d_out, int out_size, void* d_ws, size_t ws_size,
                              hipStream_t stream) {
    (void)in_sizes; (void)n_in; (void)out_size; (void)ws_size;
    const float* query = (const float*)d_in[0];
    const float* key   = (const float*)d_in[1];
    const int*   mask  = (const int*)d_in[2];
    const float* Wq  = (const float*)d_in[3];
    const float* bq  = (const float*)d_in[4];
    const float* Wk  = (const float*)d_in[5];
    const float* bk  = (const float*)d_in[6];
    const float* Wqv = (const float*)d_in[7];
    const float* bqv = (const float*)d_in[8];
    const float* Wkv = (const float*)d_in[9];
    const float* bkv = (const float*)d_in[10];

    float* out = (float*)d_out;
    float* x1 = out;
    float* x2 = out + (size_t)NN * ODIM;
    float* p  = out + (size_t)2 * NN * ODIM;

    char* ws = (char*)d_ws;
    short* qh  = (short*)(ws);
    short* kh  = (short*)(ws + (2ull << 20));
    short* qvT = (short*)(ws + (4ull << 20));
    short* kvT = (short*)(ws + (6ull << 20));
    unsigned long long* bits = (unsigned long long*)(ws + (8ull << 20));
    float* linv_ws = (float*)(ws + (10ull << 20));
    short* qvS = (short*)(ws + (10ull << 20) + (1ull << 19));
    float* x2part = (float*)(ws + (13ull << 20));   // 4 x 4 MB -> ends at 29 MB

    hipLaunchKernelGGL(pack_mask_k, dim3(NN * NN / 64 / 4), dim3(256), 0, stream, mask, bits);
    hipLaunchKernelGGL(proj_k, dim3(64, 4, 4), dim3(256), 0, stream,
                       query, key, Wq, bq, Wk, bk, Wqv, bqv, Wkv, bkv, qh, kh, qvT, kvT);
    hipLaunchKernelGGL(attn_sum_k, dim3(NN / 16, NHEAD), dim3(512), 0, stream,
                       qh, kh, bits, linv_ws);
    hipLaunchKernelGGL(scale_qv_k, dim3(512), dim3(256), 0, stream, qvT, linv_ws, qvS);
    hipLaunchKernelGGL(px2c_k, dim3(NN / 64, NHEAD, 4), dim3(512), 0, stream,
                       qh, kh, qvS, bits, x2part);
    hipLaunchKernelGGL(combine_x2_k, dim3(NN * ODIM / 4 / 256), dim3(256), 0, stream,
                       x2part, x2);
    hipLaunchKernelGGL(attn_px1_k, dim3(NN / 16, NHEAD), dim3(512), 0, stream,
                       qh, kh, kvT, bits, linv_ws, x1, p);
}

// Round 10
// 344.878 us; speedup vs baseline: 1.3948x; 1.3948x over previous
//
#include <hip/hip_runtime.h>
#include <hip/hip_bf16.h>

#define NN 4096
#define DMODEL 512
#define ODIM 256
#define NHEAD 4
#define DKH 64
#define NKW 64  // NN/64 mask words per row

typedef __attribute__((ext_vector_type(8))) short short8;
typedef __attribute__((ext_vector_type(4))) short short4v;
typedef __attribute__((ext_vector_type(8))) __bf16 bf16x8;
typedef __attribute__((ext_vector_type(4))) float f32x4;

__device__ __forceinline__ short f2bf(float f) {
    unsigned u = __builtin_bit_cast(unsigned, f);
    u += 0x7fffu + ((u >> 16) & 1u);   // RNE (no NaN in this data)
    return (short)(u >> 16);
}
__device__ __forceinline__ float bf2f(short s) {
    unsigned u = ((unsigned)(unsigned short)s) << 16;
    return __builtin_bit_cast(float, u);
}
__device__ __forceinline__ f32x4 mfma16(short8 a, short8 b, f32x4 c) {
    return __builtin_amdgcn_mfma_f32_16x16x32_bf16(
        __builtin_bit_cast(bf16x8, a), __builtin_bit_cast(bf16x8, b), c, 0, 0, 0);
}

// ---------------- mask int32 -> bitmask (1 = keep) ----------------
__global__ __launch_bounds__(256) void pack_mask_k(const int* __restrict__ mask,
                                                   unsigned long long* __restrict__ bits) {
    int tid = blockIdx.x * 256 + threadIdx.x;
    int wid = tid >> 6;
    int lane = tid & 63;
    int v = __builtin_nontemporal_load(mask + (size_t)wid * 64 + lane);
    unsigned long long b = __ballot(v != 0);
    if (lane == 0) bits[wid] = b;
}

// ---------------- 4 projections: Y = X @ W^T + b, bf16 out ----------------
__global__ __launch_bounds__(256) void proj_k(
    const float* __restrict__ Xq, const float* __restrict__ Xk,
    const float* __restrict__ Wq, const float* __restrict__ bq,
    const float* __restrict__ Wk, const float* __restrict__ bk,
    const float* __restrict__ Wqv, const float* __restrict__ bqv,
    const float* __restrict__ Wkv, const float* __restrict__ bkv,
    short* __restrict__ qh, short* __restrict__ kh,
    short* __restrict__ qvT, short* __restrict__ kvT) {
    int z = blockIdx.z;
    const float *X, *W, *B;
    short* out;
    int tr;
    float postscale = 1.f;
    switch (z) {
        case 0: X = Xq; W = Wq;  B = bq;  out = qh;  tr = 0; postscale = 0.125f; break;
        case 1: X = Xk; W = Wk;  B = bk;  out = kh;  tr = 0; break;
        case 2: X = Xq; W = Wqv; B = bqv; out = qvT; tr = 1; break;
        default: X = Xk; W = Wkv; B = bkv; out = kvT; tr = 1; break;
    }
    int lane = threadIdx.x & 63, w = threadIdx.x >> 6;
    int lr = lane & 15, lg = lane >> 4;
    int m0 = blockIdx.x * 64 + (w >> 1) * 32;
    int n0 = blockIdx.y * 64 + (w & 1) * 32;

    f32x4 acc[2][2] = {};
    for (int kk = 0; kk < DMODEL; kk += 32) {
        short8 a[2], b[2];
#pragma unroll
        for (int i = 0; i < 2; i++) {
            const float* pa = X + (size_t)(m0 + i * 16 + lr) * DMODEL + kk + lg * 8;
            const float* pb = W + (size_t)(n0 + i * 16 + lr) * DMODEL + kk + lg * 8;
            float4 a0 = *(const float4*)pa;
            float4 a1 = *(const float4*)(pa + 4);
            float4 b0 = *(const float4*)pb;
            float4 b1 = *(const float4*)(pb + 4);
            a[i][0] = f2bf(a0.x); a[i][1] = f2bf(a0.y); a[i][2] = f2bf(a0.z); a[i][3] = f2bf(a0.w);
            a[i][4] = f2bf(a1.x); a[i][5] = f2bf(a1.y); a[i][6] = f2bf(a1.z); a[i][7] = f2bf(a1.w);
            b[i][0] = f2bf(b0.x); b[i][1] = f2bf(b0.y); b[i][2] = f2bf(b0.z); b[i][3] = f2bf(b0.w);
            b[i][4] = f2bf(b1.x); b[i][5] = f2bf(b1.y); b[i][6] = f2bf(b1.z); b[i][7] = f2bf(b1.w);
        }
#pragma unroll
        for (int i = 0; i < 2; i++)
#pragma unroll
            for (int j = 0; j < 2; j++) acc[i][j] = mfma16(a[i], b[j], acc[i][j]);
    }
#pragma unroll
    for (int i = 0; i < 2; i++)
#pragma unroll
        for (int j = 0; j < 2; j++) {
            int col = n0 + j * 16 + lr;
            float bv = B[col];
            int hh = col >> 6, dk = col & 63;
#pragma unroll
            for (int r = 0; r < 4; r++) {
                int row = m0 + i * 16 + lg * 4 + r;
                short s = f2bf((acc[i][j][r] + bv) * postscale);
                if (!tr) out[((size_t)hh * NN + row) * DKH + dk] = s;
                else     out[((size_t)hh * DKH + dk) * NN + row] = s;
            }
        }
}

// ================= PRIMARY PATH =================
// Kernel A: single sweep. Per (head, 16-q strip), 8 waves; wave w owns k-tiles
// [w*8, w*8+8). QK^T + exp ONCE, stores unnormalized p~ (bf16) in KEY-MAJOR
// tile pbuf [h][strip][ktile][key 64][q 16] via LDS transpose (2x16B vector
// stores/lane/tile), accumulates denom + unnormalized x1. Tail: double-
// buffered re-read of own tiles, normalize, 256B-coalesced f32 p stores.
__global__ __launch_bounds__(512) void attn_fused_k(
    const short* __restrict__ qh, const short* __restrict__ kh, const short* __restrict__ kvT,
    const unsigned long long* __restrict__ bits,
    short* __restrict__ pbuf, float* __restrict__ linv_ws,
    float* __restrict__ x1_out, float* __restrict__ p_out) {
    int h = blockIdx.y;
    int strip = blockIdx.x;
    int tid = threadIdx.x, lane = tid & 63, w = tid >> 6;  // w in 0..7
    int lr = lane & 15, lg = lane >> 4;
    int q0 = strip * 16;

    __shared__ float smemf[4608];                       // 18 KB union
    short (*plds)[16][72] = (short (*)[16][72])smemf;   // [8][16][72] bf16
    float (*xbuf)[64][17] = (float (*)[64][17])smemf;   // [4][64][17] f32
    __shared__ float sl[8][16];
    __shared__ float linv_s[16];

    const short* khh = kh + (size_t)h * NN * DKH;
    const unsigned long long* brow = bits + (size_t)(q0 + lr) * NKW;
    short* ptile0 = pbuf + (((size_t)(h * 256 + strip) * 64) << 10);

    short8 bq[2];
#pragma unroll
    for (int kk = 0; kk < 2; kk++)
        bq[kk] = *(const short8*)(qh + ((size_t)h * NN + q0 + lr) * DKH + kk * 32 + lg * 8);

    float lrun = 0.f;
    f32x4 acc1[4] = {};
    for (int t = 0; t < 8; t++) {
        int kt = w * 8 + t;
        f32x4 s[4] = {};
#pragma unroll
        for (int fj = 0; fj < 4; fj++)
#pragma unroll
            for (int kk = 0; kk < 2; kk++) {
                short8 a = *(const short8*)(khh + (size_t)(kt * 64 + fj * 16 + lr) * DKH + kk * 32 + lg * 8);
                s[fj] = mfma16(a, bq[kk], s[fj]);
            }
        unsigned long long mw = brow[kt] >> (lg * 4);
#pragma unroll
        for (int fj = 0; fj < 4; fj++) {
            short4v pb4;
#pragma unroll
            for (int r = 0; r < 4; r++) {
                bool keep = (mw >> (fj * 16 + r)) & 1ull;
                float e = __expf(keep ? s[fj][r] : -100.f);
                lrun += e;
                pb4[r] = f2bf(e);
            }
            *(short4v*)&plds[w][lr][fj * 16 + lg * 4] = pb4;
        }
        // x1 += p~ @ kv (wave-private LDS strip; loads before the pbuf stores)
#pragma unroll
        for (int kk = 0; kk < 2; kk++) {
            short8 a1 = *(const short8*)&plds[w][lr][kk * 32 + lg * 8];
#pragma unroll
            for (int fd = 0; fd < 4; fd++) {
                short8 bv = *(const short8*)(kvT + ((size_t)h * DKH + fd * 16 + lr) * NN + kt * 64 + kk * 32 + lg * 8);
                acc1[fd] = mfma16(a1, bv, acc1[fd]);
            }
        }
        // pbuf tile write via LDS transpose: lane = key, 2 x 16B stores
        {
            short8 v0, v1;
#pragma unroll
            for (int j = 0; j < 8; j++) v0[j] = plds[w][j][lane];
#pragma unroll
            for (int j = 0; j < 8; j++) v1[j] = plds[w][8 + j][lane];
            short* ptile = ptile0 + ((size_t)kt << 10) + lane * 16;
            *(short8*)(ptile) = v0;
            *(short8*)(ptile + 8) = v1;
        }
    }
    // ---- denominator reduce ----
    lrun += __shfl_xor(lrun, 16);
    lrun += __shfl_xor(lrun, 32);
    if (lg == 0) sl[w][lr] = lrun;
    __syncthreads();
    float l = 0.f;
#pragma unroll
    for (int w2 = 0; w2 < 8; w2++) l += sl[w2][lr];
    float linv = l > 0.f ? 1.f / l : 0.f;
    if (w == 0 && lg == 0) {
        linv_s[lr] = linv;
        linv_ws[(size_t)h * NN + q0 + lr] = linv;
    }
    __syncthreads();

    // ---- streaming tail: normalize own tiles -> f32 p (double-buffered) ----
    asm volatile("s_waitcnt vmcnt(0)" ::: "memory");
    float linvv[16];
#pragma unroll
    for (int j = 0; j < 16; j++) linvv[j] = linv_s[j];
    const short* tl0 = ptile0 + ((size_t)(w * 8) << 10) + lane * 16;
    short8 pv0 = *(const short8*)(tl0);
    short8 pv1 = *(const short8*)(tl0 + 8);
    for (int t = 0; t < 8; t++) {
        int kt = w * 8 + t;
        short8 n0 = pv0, n1 = pv1;
        if (t < 7) {
            const short* tn = ptile0 + ((size_t)(kt + 1) << 10) + lane * 16;
            n0 = *(const short8*)(tn);
            n1 = *(const short8*)(tn + 8);
        }
        float* pd = p_out + ((size_t)h * NN + q0) * NN + kt * 64 + lane;
#pragma unroll
        for (int j = 0; j < 8; j++) pd[(size_t)j * NN] = bf2f(pv0[j]) * linvv[j];
#pragma unroll
        for (int j = 0; j < 8; j++) pd[(size_t)(8 + j) * NN] = bf2f(pv1[j]) * linvv[8 + j];
        pv0 = n0; pv1 = n1;
    }

    // ---- two-phase staggered cross-wave x1 reduce (reuses plds memory) ----
    __syncthreads();
    if (w >= 4) {
#pragma unroll
        for (int fd = 0; fd < 4; fd++)
#pragma unroll
            for (int r = 0; r < 4; r++) xbuf[w - 4][lane][fd * 4 + r] = acc1[fd][r];
    }
    __syncthreads();
    if (w < 4) {
#pragma unroll
        for (int fd = 0; fd < 4; fd++)
#pragma unroll
            for (int r = 0; r < 4; r++) acc1[fd][r] += xbuf[w][lane][fd * 4 + r];
    }
    __syncthreads();
    if (w >= 1 && w < 4) {
#pragma unroll
        for (int fd = 0; fd < 4; fd++)
#pragma unroll
            for (int r = 0; r < 4; r++) xbuf[w - 1][lane][fd * 4 + r] = acc1[fd][r];
    }
    __syncthreads();
    if (w == 0) {
#pragma unroll
        for (int fd = 0; fd < 4; fd++)
#pragma unroll
            for (int r = 0; r < 4; r++) {
                float v = acc1[fd][r] + xbuf[0][lane][fd * 4 + r] + xbuf[1][lane][fd * 4 + r] +
                          xbuf[2][lane][fd * 4 + r];
                v *= linv_s[lg * 4 + r];
                v = v > 0.f ? v : (__expf(v) - 1.f);
                x1_out[(size_t)(q0 + lg * 4 + r) * ODIM + h * DKH + fd * 16 + lr] = v;
            }
    }
}

// scale qv by linv along q: qvS[h][d][q] = qvT[h][d][q] * linv[h][q]
__global__ __launch_bounds__(256) void scale_qv_k(const short* __restrict__ qvT,
                                                  const float* __restrict__ linv,
                                                  short* __restrict__ qvS) {
    int idx = blockIdx.x * 256 + threadIdx.x;   // 131072 threads, short8 each
    int q8 = idx & 511;
    int dh = idx >> 9;                          // h*64 + d
    int h = dh >> 6;
    short8 v = *(const short8*)(qvT + (size_t)dh * NN + q8 * 8);
    const float* lp = linv + (size_t)h * NN + q8 * 8;
    float4 l0 = *(const float4*)lp;
    float4 l1 = *(const float4*)(lp + 4);
    short8 o;
    o[0] = f2bf(bf2f(v[0]) * l0.x); o[1] = f2bf(bf2f(v[1]) * l0.y);
    o[2] = f2bf(bf2f(v[2]) * l0.z); o[3] = f2bf(bf2f(v[3]) * l0.w);
    o[4] = f2bf(bf2f(v[4]) * l1.x); o[5] = f2bf(bf2f(v[5]) * l1.y);
    o[6] = f2bf(bf2f(v[6]) * l1.z); o[7] = f2bf(bf2f(v[7]) * l1.w);
    *(short8*)(qvS + (size_t)dh * NN + q8 * 8) = o;
}

// px2b: x2part[z] = p~^T @ qvS over q in [z*1024,(z+1)*1024).
// Pure streaming GEMM on key-major pbuf, register double-buffered (A+B
// prefetch issued before the MFMAs of the current iteration).
__global__ __launch_bounds__(512) void px2b_k(
    const short* __restrict__ pbuf, const short* __restrict__ qvS,
    float* __restrict__ x2part) {
    int kt = blockIdx.x, h = blockIdx.y, z = blockIdx.z;
    int tid = threadIdx.x, lane = tid & 63, w = tid >> 6;
    int fj = w & 3, sh = w >> 2;
    int lr = lane & 15, lg = lane >> 4;

    __shared__ float red[4][64][17];   // 17,408 B

    const short* qvh = qvS + (size_t)h * DKH * NN;
    f32x4 acc[4] = {};
    int qbase = z * 1024 + sh * 512;

    // prologue: load it=0
    int qq0 = qbase;
    int strip0 = (qq0 >> 4) + (lg >> 1);
    short8 afc = *(const short8*)(pbuf + (((size_t)(h * 256 + strip0) * 64 + kt) << 10) +
                                  (fj * 16 + lr) * 16 + (lg & 1) * 8);
    short8 bvc0 = *(const short8*)(qvh + (size_t)(0 * 16 + lr) * NN + qq0 + lg * 8);
    short8 bvc1 = *(const short8*)(qvh + (size_t)(1 * 16 + lr) * NN + qq0 + lg * 8);
    short8 bvc2 = *(const short8*)(qvh + (size_t)(2 * 16 + lr) * NN + qq0 + lg * 8);
    short8 bvc3 = *(const short8*)(qvh + (size_t)(3 * 16 + lr) * NN + qq0 + lg * 8);

    for (int it = 0; it < 16; it++) {
        short8 afn = afc, bvn0 = bvc0, bvn1 = bvc1, bvn2 = bvc2, bvn3 = bvc3;
        if (it < 15) {
            int qq = qbase + (it + 1) * 32;
            int strip = (qq >> 4) + (lg >> 1);
            afn = *(const short8*)(pbuf + (((size_t)(h * 256 + strip) * 64 + kt) << 10) +
                                   (fj * 16 + lr) * 16 + (lg & 1) * 8);
            bvn0 = *(const short8*)(qvh + (size_t)(0 * 16 + lr) * NN + qq + lg * 8);
            bvn1 = *(const short8*)(qvh + (size_t)(1 * 16 + lr) * NN + qq + lg * 8);
            bvn2 = *(const short8*)(qvh + (size_t)(2 * 16 + lr) * NN + qq + lg * 8);
            bvn3 = *(const short8*)(qvh + (size_t)(3 * 16 + lr) * NN + qq + lg * 8);
        }
        acc[0] = mfma16(afc, bvc0, acc[0]);
        acc[1] = mfma16(afc, bvc1, acc[1]);
        acc[2] = mfma16(afc, bvc2, acc[2]);
        acc[3] = mfma16(afc, bvc3, acc[3]);
        afc = afn; bvc0 = bvn0; bvc1 = bvn1; bvc2 = bvn2; bvc3 = bvn3;
    }
    // ---- combine sh halves ----
    if (sh == 1) {
#pragma unroll
        for (int fd = 0; fd < 4; fd++)
#pragma unroll
            for (int r = 0; r < 4; r++) red[fj][lane][fd * 4 + r] = acc[fd][r];
    }
    __syncthreads();
    if (sh == 0) {
        float* xp = x2part + (size_t)z * NN * ODIM;
#pragma unroll
        for (int fd = 0; fd < 4; fd++)
#pragma unroll
            for (int r = 0; r < 4; r++) {
                float v = acc[fd][r] + red[fj][lane][fd * 4 + r];
                xp[(size_t)(kt * 64 + fj * 16 + lg * 4 + r) * ODIM + h * DKH + fd * 16 + lr] = v;
            }
    }
}

// combine: x2 = ELU(part0 + part1 + part2 + part3)
__global__ __launch_bounds__(256) void combine_x2_k(const float* __restrict__ x2part,
                                                    float* __restrict__ x2_out) {
    int idx = blockIdx.x * 256 + threadIdx.x;   // 262144 threads, float4 each
    size_t i = (size_t)idx * 4;
    const size_t stride = (size_t)NN * ODIM;
    float4 a = *(const float4*)(x2part + i);
    float4 b = *(const float4*)(x2part + stride + i);
    float4 c = *(const float4*)(x2part + 2 * stride + i);
    float4 d = *(const float4*)(x2part + 3 * stride + i);
    float4 o;
    o.x = a.x + b.x + c.x + d.x;
    o.y = a.y + b.y + c.y + d.y;
    o.z = a.z + b.z + c.z + d.z;
    o.w = a.w + b.w + c.w + d.w;
    o.x = o.x > 0.f ? o.x : (__expf(o.x) - 1.f);
    o.y = o.y > 0.f ? o.y : (__expf(o.y) - 1.f);
    o.z = o.z > 0.f ? o.z : (__expf(o.z) - 1.f);
    o.w = o.w > 0.f ? o.w : (__expf(o.w) - 1.f);
    *(float4*)(x2_out + i) = o;
}

// ================= FALLBACK PATH (known-good) =================
__global__ __launch_bounds__(512) void attn_fb_k(
    const short* __restrict__ qh, const short* __restrict__ kh, const short* __restrict__ kvT,
    const unsigned long long* __restrict__ bits,
    float* __restrict__ x1_out, float* __restrict__ p_out) {
    int h = blockIdx.y;
    int tid = threadIdx.x, lane = tid & 63, w = tid >> 6;
    int lr = lane & 15, lg = lane >> 4;
    int q0 = blockIdx.x * 16;

    __shared__ float smemf[4608];
    short (*plds)[16][72] = (short (*)[16][72])smemf;
    float (*xbuf)[64][17] = (float (*)[64][17])smemf;
    __shared__ float sl[8][16];

    const short* khh = kh + (size_t)h * NN * DKH;
    const unsigned long long* brow = bits + (size_t)(q0 + lr) * NKW;

    short8 bq[2];
#pragma unroll
    for (int kk = 0; kk < 2; kk++)
        bq[kk] = *(const short8*)(qh + ((size_t)h * NN + q0 + lr) * DKH + kk * 32 + lg * 8);

    float lrun = 0.f;
    for (int t = 0; t < 8; t++) {
        int kt = w * 8 + t;
        f32x4 s[4] = {};
#pragma unroll
        for (int fj = 0; fj < 4; fj++)
#pragma unroll
            for (int kk = 0; kk < 2; kk++) {
                short8 a = *(const short8*)(khh + (size_t)(kt * 64 + fj * 16 + lr) * DKH + kk * 32 + lg * 8);
                s[fj] = mfma16(a, bq[kk], s[fj]);
            }
        unsigned long long mw = brow[kt] >> (lg * 4);
#pragma unroll
        for (int fj = 0; fj < 4; fj++)
#pragma unroll
            for (int r = 0; r < 4; r++) {
                bool keep = (mw >> (fj * 16 + r)) & 1ull;
                lrun += __expf(keep ? s[fj][r] : -100.f);
            }
    }
    lrun += __shfl_xor(lrun, 16);
    lrun += __shfl_xor(lrun, 32);
    if (lg == 0) sl[w][lr] = lrun;
    __syncthreads();
    float l = 0.f;
#pragma unroll
    for (int w2 = 0; w2 < 8; w2++) l += sl[w2][lr];
    float linv = l > 0.f ? 1.f / l : 0.f;

    f32x4 acc1[4] = {};
    float* prow = p_out + ((size_t)h * NN + q0 + lr) * NN;
    for (int t = 0; t < 8; t++) {
        int kt = w * 8 + t;
        f32x4 s[4] = {};
#pragma unroll
        for (int fj = 0; fj < 4; fj++)
#pragma unroll
            for (int kk = 0; kk < 2; kk++) {
                short8 a = *(const short8*)(khh + (size_t)(kt * 64 + fj * 16 + lr) * DKH + kk * 32 + lg * 8);
                s[fj] = mfma16(a, bq[kk], s[fj]);
            }
        unsigned long long mw = brow[kt] >> (lg * 4);
#pragma unroll
        for (int fj = 0; fj < 4; fj++) {
            float4 pv;
            short4v pb;
#pragma unroll
            for (int r = 0; r < 4; r++) {
                bool keep = (mw >> (fj * 16 + r)) & 1ull;
                float p = __expf(keep ? s[fj][r] : -100.f) * linv;
                (&pv.x)[r] = p;
                pb[r] = f2bf(p);
            }
            *(float4*)(prow + kt * 64 + fj * 16 + lg * 4) = pv;
            *(short4v*)&plds[w][lr][fj * 16 + lg * 4] = pb;
        }
#pragma unroll
        for (int kk = 0; kk < 2; kk++) {
            short8 a1 = *(const short8*)&plds[w][lr][kk * 32 + lg * 8];
#pragma unroll
            for (int fd = 0; fd < 4; fd++) {
                short8 bv = *(const short8*)(kvT + ((size_t)h * DKH + fd * 16 + lr) * NN + kt * 64 + kk * 32 + lg * 8);
                acc1[fd] = mfma16(a1, bv, acc1[fd]);
            }
        }
    }
    __syncthreads();
    if (w >= 4) {
#pragma unroll
        for (int fd = 0; fd < 4; fd++)
#pragma unroll
            for (int r = 0; r < 4; r++) xbuf[w - 4][lane][fd * 4 + r] = acc1[fd][r];
    }
    __syncthreads();
    if (w < 4) {
#pragma unroll
        for (int fd = 0; fd < 4; fd++)
#pragma unroll
            for (int r = 0; r < 4; r++) acc1[fd][r] += xbuf[w][lane][fd * 4 + r];
    }
    __syncthreads();
    if (w >= 1 && w < 4) {
#pragma unroll
        for (int fd = 0; fd < 4; fd++)
#pragma unroll
            for (int r = 0; r < 4; r++) xbuf[w - 1][lane][fd * 4 + r] = acc1[fd][r];
    }
    __syncthreads();
    if (w == 0) {
#pragma unroll
        for (int fd = 0; fd < 4; fd++)
#pragma unroll
            for (int r = 0; r < 4; r++) {
                float v = acc1[fd][r] + xbuf[0][lane][fd * 4 + r] + xbuf[1][lane][fd * 4 + r] +
                          xbuf[2][lane][fd * 4 + r];
                v = v > 0.f ? v : (__expf(v) - 1.f);
                x1_out[(size_t)(q0 + lg * 4 + r) * ODIM + h * DKH + fd * 16 + lr] = v;
            }
    }
}

__global__ __launch_bounds__(512) void px2_fb_k(
    const float* __restrict__ p, const short* __restrict__ qvT,
    float* __restrict__ x2_out) {
    int h = blockIdx.y;
    int k0 = blockIdx.x * 32;
    int tid = threadIdx.x, lane = tid & 63, w = tid >> 6;
    int lr = lane & 15, lg = lane >> 4;

    __shared__ float red[4][64][33];

    f32x4 acc[2][4] = {};
    const float* pbase = p + (size_t)h * NN * NN;
    const short* qvh = qvT + (size_t)h * DKH * NN;

    for (int it = 0; it < 16; it++) {
        int qq = w * 512 + it * 32;
        short8 aP[2];
#pragma unroll
        for (int fj = 0; fj < 2; fj++) {
            const float* pp = pbase + (size_t)(qq + lg * 8) * NN + k0 + fj * 16 + lr;
            short8 av;
#pragma unroll
            for (int j = 0; j < 8; j++) av[j] = f2bf(pp[j * NN]);
            aP[fj] = av;
        }
#pragma unroll
        for (int fd = 0; fd < 4; fd++) {
            short8 bv = *(const short8*)(qvh + (size_t)(fd * 16 + lr) * NN + qq + lg * 8);
#pragma unroll
            for (int fj = 0; fj < 2; fj++) acc[fj][fd] = mfma16(aP[fj], bv, acc[fj][fd]);
        }
    }
    if (w >= 4) {
#pragma unroll
        for (int fj = 0; fj < 2; fj++)
#pragma unroll
            for (int fd = 0; fd < 4; fd++)
#pragma unroll
                for (int r = 0; r < 4; r++)
                    red[w - 4][lane][fj * 16 + fd * 4 + r] = acc[fj][fd][r];
    }
    __syncthreads();
    if (w < 4) {
#pragma unroll
        for (int fj = 0; fj < 2; fj++)
#pragma unroll
            for (int fd = 0; fd < 4; fd++)
#pragma unroll
                for (int r = 0; r < 4; r++)
                    acc[fj][fd][r] += red[w][lane][fj * 16 + fd * 4 + r];
    }
    __syncthreads();
    if (w >= 1 && w < 4) {
#pragma unroll
        for (int fj = 0; fj < 2; fj++)
#pragma unroll
            for (int fd = 0; fd < 4; fd++)
#pragma unroll
                for (int r = 0; r < 4; r++)
                    red[w - 1][lane][fj * 16 + fd * 4 + r] = acc[fj][fd][r];
    }
    __syncthreads();
    if (w == 0) {
#pragma unroll
        for (int fj = 0; fj < 2; fj++)
#pragma unroll
            for (int fd = 0; fd < 4; fd++)
#pragma unroll
                for (int r = 0; r < 4; r++) {
                    float v = acc[fj][fd][r];
#pragma unroll
                    for (int s2 = 0; s2 < 3; s2++) v += red[s2][lane][fj * 16 + fd * 4 + r];
                    v = v > 0.f ? v : (__expf(v) - 1.f);
                    x2_out[(size_t)(k0 + fj * 16 + lg * 4 + r) * ODIM + h * DKH + fd * 16 + lr] = v;
                }
    }
}

extern "C" void kernel_launch(void* const* d_in, const int* in_sizes, int n_in,
                              void* d_out, int out_size, void* d_ws, size_t ws_size,
                              hipStream_t stream) {
    (void)in_sizes; (void)n_in; (void)out_size;
    const float* query = (const float*)d_in[0];
    const float* key   = (const float*)d_in[1];
    const int*   mask  = (const int*)d_in[2];
    const float* Wq  = (const float*)d_in[3];
    const float* bq  = (const float*)d_in[4];
    const float* Wk  = (const float*)d_in[5];
    const float* bk  = (const float*)d_in[6];
    const float* Wqv = (const float*)d_in[7];
    const float* bqv = (const float*)d_in[8];
    const float* Wkv = (const float*)d_in[9];
    const float* bkv = (const float*)d_in[10];

    float* out = (float*)d_out;
    float* x1 = out;
    float* x2 = out + (size_t)NN * ODIM;
    float* p  = out + (size_t)2 * NN * ODIM;

    char* ws = (char*)d_ws;
    short* qh  = (short*)(ws);
    short* kh  = (short*)(ws + (2ull << 20));
    short* qvT = (short*)(ws + (4ull << 20));
    short* kvT = (short*)(ws + (6ull << 20));
    unsigned long long* bits = (unsigned long long*)(ws + (8ull << 20));
    float* linv_ws = (float*)(ws + (10ull << 20));
    short* qvS = (short*)(ws + (10ull << 20) + (1ull << 19));
    float* x2part = (float*)(ws + (13ull << 20));            // 4 x 4 MB
    short* pbuf = (short*)(ws + (29ull << 20));               // 128 MB
    size_t need = (29ull << 20) + (size_t)NHEAD * NN * NN * sizeof(short);

    hipLaunchKernelGGL(pack_mask_k, dim3(NN * NN / 64 / 4), dim3(256), 0, stream, mask, bits);
    hipLaunchKernelGGL(proj_k, dim3(64, 4, 4), dim3(256), 0, stream,
                       query, key, Wq, bq, Wk, bk, Wqv, bqv, Wkv, bkv, qh, kh, qvT, kvT);

    if (ws_size >= need) {
        hipLaunchKernelGGL(attn_fused_k, dim3(NN / 16, NHEAD), dim3(512), 0, stream,
                           qh, kh, kvT, bits, pbuf, linv_ws, x1, p);
        hipLaunchKernelGGL(scale_qv_k, dim3(512), dim3(256), 0, stream, qvT, linv_ws, qvS);
        hipLaunchKernelGGL(px2b_k, dim3(NN / 64, NHEAD, 4), dim3(512), 0, stream,
                           pbuf, qvS, x2part);
        hipLaunchKernelGGL(combine_x2_k, dim3(NN * ODIM / 4 / 256), dim3(256), 0, stream,
                           x2part, x2);
    } else {
        hipLaunchKernelGGL(attn_fb_k, dim3(NN / 16, NHEAD), dim3(512), 0, stream,
                           qh, kh, kvT, bits, x1, p);
        hipLaunchKernelGGL(px2_fb_k, dim3(NN / 32, NHEAD), dim3(512), 0, stream,
                           p, qvT, x2);
    }
}

// Round 12
// 324.631 us; speedup vs baseline: 1.4818x; 1.0624x over previous
//
#include <hip/hip_runtime.h>
#include <hip/hip_bf16.h>

#define NN 4096
#define DMODEL 512
#define ODIM 256
#define NHEAD 4
#define DKH 64
#define NKW 64  // NN/64 mask words per row

typedef __attribute__((ext_vector_type(8))) short short8;
typedef __attribute__((ext_vector_type(4))) short short4v;
typedef __attribute__((ext_vector_type(8))) __bf16 bf16x8;
typedef __attribute__((ext_vector_type(4))) float f32x4;

__device__ __forceinline__ short f2bf(float f) {
    unsigned u = __builtin_bit_cast(unsigned, f);
    u += 0x7fffu + ((u >> 16) & 1u);   // RNE (no NaN in this data)
    return (short)(u >> 16);
}
__device__ __forceinline__ float bf2f(short s) {
    unsigned u = ((unsigned)(unsigned short)s) << 16;
    return __builtin_bit_cast(float, u);
}
__device__ __forceinline__ f32x4 mfma16(short8 a, short8 b, f32x4 c) {
    return __builtin_amdgcn_mfma_f32_16x16x32_bf16(
        __builtin_bit_cast(bf16x8, a), __builtin_bit_cast(bf16x8, b), c, 0, 0, 0);
}

// ---------------- mask int32 -> bitmask (1 = keep) ----------------
__global__ __launch_bounds__(256) void pack_mask_k(const int* __restrict__ mask,
                                                   unsigned long long* __restrict__ bits) {
    int tid = blockIdx.x * 256 + threadIdx.x;
    int wid = tid >> 6;
    int lane = tid & 63;
    int v = __builtin_nontemporal_load(mask + (size_t)wid * 64 + lane);
    unsigned long long b = __ballot(v != 0);
    if (lane == 0) bits[wid] = b;
}

// ---------------- 4 projections: Y = X @ W^T + b, bf16 out (R10 epilogue) ----------------
__global__ __launch_bounds__(256) void proj_k(
    const float* __restrict__ Xq, const float* __restrict__ Xk,
    const float* __restrict__ Wq, const float* __restrict__ bq,
    const float* __restrict__ Wk, const float* __restrict__ bk,
    const float* __restrict__ Wqv, const float* __restrict__ bqv,
    const float* __restrict__ Wkv, const float* __restrict__ bkv,
    short* __restrict__ qh, short* __restrict__ kh,
    short* __restrict__ qvT, short* __restrict__ kvT) {
    int z = blockIdx.z;
    const float *X, *W, *B;
    short* out;
    int tr;
    float postscale = 1.f;
    switch (z) {
        case 0: X = Xq; W = Wq;  B = bq;  out = qh;  tr = 0; postscale = 0.125f; break;
        case 1: X = Xk; W = Wk;  B = bk;  out = kh;  tr = 0; break;
        case 2: X = Xq; W = Wqv; B = bqv; out = qvT; tr = 1; break;
        default: X = Xk; W = Wkv; B = bkv; out = kvT; tr = 1; break;
    }
    int lane = threadIdx.x & 63, w = threadIdx.x >> 6;
    int lr = lane & 15, lg = lane >> 4;
    int m0 = blockIdx.x * 64 + (w >> 1) * 32;
    int n0 = blockIdx.y * 64 + (w & 1) * 32;

    f32x4 acc[2][2] = {};
    for (int kk = 0; kk < DMODEL; kk += 32) {
        short8 a[2], b[2];
#pragma unroll
        for (int i = 0; i < 2; i++) {
            const float* pa = X + (size_t)(m0 + i * 16 + lr) * DMODEL + kk + lg * 8;
            const float* pb = W + (size_t)(n0 + i * 16 + lr) * DMODEL + kk + lg * 8;
            float4 a0 = *(const float4*)pa;
            float4 a1 = *(const float4*)(pa + 4);
            float4 b0 = *(const float4*)pb;
            float4 b1 = *(const float4*)(pb + 4);
            a[i][0] = f2bf(a0.x); a[i][1] = f2bf(a0.y); a[i][2] = f2bf(a0.z); a[i][3] = f2bf(a0.w);
            a[i][4] = f2bf(a1.x); a[i][5] = f2bf(a1.y); a[i][6] = f2bf(a1.z); a[i][7] = f2bf(a1.w);
            b[i][0] = f2bf(b0.x); b[i][1] = f2bf(b0.y); b[i][2] = f2bf(b0.z); b[i][3] = f2bf(b0.w);
            b[i][4] = f2bf(b1.x); b[i][5] = f2bf(b1.y); b[i][6] = f2bf(b1.z); b[i][7] = f2bf(b1.w);
        }
#pragma unroll
        for (int i = 0; i < 2; i++)
#pragma unroll
            for (int j = 0; j < 2; j++) acc[i][j] = mfma16(a[i], b[j], acc[i][j]);
    }
#pragma unroll
    for (int i = 0; i < 2; i++)
#pragma unroll
        for (int j = 0; j < 2; j++) {
            int col = n0 + j * 16 + lr;
            float bv = B[col];
            int hh = col >> 6, dk = col & 63;
#pragma unroll
            for (int r = 0; r < 4; r++) {
                int row = m0 + i * 16 + lg * 4 + r;
                short s = f2bf((acc[i][j][r] + bv) * postscale);
                if (!tr) out[((size_t)hh * NN + row) * DKH + dk] = s;
                else     out[((size_t)hh * DKH + dk) * NN + row] = s;
            }
        }
}

// ================= PRIMARY PATH =================
// Kernel A (R10, known-good): single sweep, key-major pbuf via LDS transpose,
// denom + x1, double-buffered normalize tail.
__global__ __launch_bounds__(512) void attn_fused_k(
    const short* __restrict__ qh, const short* __restrict__ kh, const short* __restrict__ kvT,
    const unsigned long long* __restrict__ bits,
    short* __restrict__ pbuf, float* __restrict__ linv_ws,
    float* __restrict__ x1_out, float* __restrict__ p_out) {
    int h = blockIdx.y;
    int strip = blockIdx.x;
    int tid = threadIdx.x, lane = tid & 63, w = tid >> 6;  // w in 0..7
    int lr = lane & 15, lg = lane >> 4;
    int q0 = strip * 16;

    __shared__ float smemf[4608];                       // 18 KB union
    short (*plds)[16][72] = (short (*)[16][72])smemf;   // [8][16][72] bf16
    float (*xbuf)[64][17] = (float (*)[64][17])smemf;   // [4][64][17] f32
    __shared__ float sl[8][16];
    __shared__ float linv_s[16];

    const short* khh = kh + (size_t)h * NN * DKH;
    const unsigned long long* brow = bits + (size_t)(q0 + lr) * NKW;
    short* ptile0 = pbuf + (((size_t)(h * 256 + strip) * 64) << 10);

    short8 bq[2];
#pragma unroll
    for (int kk = 0; kk < 2; kk++)
        bq[kk] = *(const short8*)(qh + ((size_t)h * NN + q0 + lr) * DKH + kk * 32 + lg * 8);

    float lrun = 0.f;
    f32x4 acc1[4] = {};
    for (int t = 0; t < 8; t++) {
        int kt = w * 8 + t;
        f32x4 s[4] = {};
#pragma unroll
        for (int fj = 0; fj < 4; fj++)
#pragma unroll
            for (int kk = 0; kk < 2; kk++) {
                short8 a = *(const short8*)(khh + (size_t)(kt * 64 + fj * 16 + lr) * DKH + kk * 32 + lg * 8);
                s[fj] = mfma16(a, bq[kk], s[fj]);
            }
        unsigned long long mw = brow[kt] >> (lg * 4);
#pragma unroll
        for (int fj = 0; fj < 4; fj++) {
            short4v pb4;
#pragma unroll
            for (int r = 0; r < 4; r++) {
                bool keep = (mw >> (fj * 16 + r)) & 1ull;
                float e = __expf(keep ? s[fj][r] : -100.f);
                lrun += e;
                pb4[r] = f2bf(e);
            }
            *(short4v*)&plds[w][lr][fj * 16 + lg * 4] = pb4;
        }
        // x1 += p~ @ kv (wave-private LDS strip; loads before the pbuf stores)
#pragma unroll
        for (int kk = 0; kk < 2; kk++) {
            short8 a1 = *(const short8*)&plds[w][lr][kk * 32 + lg * 8];
#pragma unroll
            for (int fd = 0; fd < 4; fd++) {
                short8 bv = *(const short8*)(kvT + ((size_t)h * DKH + fd * 16 + lr) * NN + kt * 64 + kk * 32 + lg * 8);
                acc1[fd] = mfma16(a1, bv, acc1[fd]);
            }
        }
        // pbuf tile write via LDS transpose: lane = key, 2 x 16B stores
        {
            short8 v0, v1;
#pragma unroll
            for (int j = 0; j < 8; j++) v0[j] = plds[w][j][lane];
#pragma unroll
            for (int j = 0; j < 8; j++) v1[j] = plds[w][8 + j][lane];
            short* ptile = ptile0 + ((size_t)kt << 10) + lane * 16;
            *(short8*)(ptile) = v0;
            *(short8*)(ptile + 8) = v1;
        }
    }
    // ---- denominator reduce ----
    lrun += __shfl_xor(lrun, 16);
    lrun += __shfl_xor(lrun, 32);
    if (lg == 0) sl[w][lr] = lrun;
    __syncthreads();
    float l = 0.f;
#pragma unroll
    for (int w2 = 0; w2 < 8; w2++) l += sl[w2][lr];
    float linv = l > 0.f ? 1.f / l : 0.f;
    if (w == 0 && lg == 0) {
        linv_s[lr] = linv;
        linv_ws[(size_t)h * NN + q0 + lr] = linv;
    }
    __syncthreads();

    // ---- streaming tail: normalize own tiles -> f32 p (double-buffered) ----
    asm volatile("s_waitcnt vmcnt(0)" ::: "memory");
    float linvv[16];
#pragma unroll
    for (int j = 0; j < 16; j++) linvv[j] = linv_s[j];
    const short* tl0 = ptile0 + ((size_t)(w * 8) << 10) + lane * 16;
    short8 pv0 = *(const short8*)(tl0);
    short8 pv1 = *(const short8*)(tl0 + 8);
    for (int t = 0; t < 8; t++) {
        int kt = w * 8 + t;
        short8 n0 = pv0, n1 = pv1;
        if (t < 7) {
            const short* tn = ptile0 + ((size_t)(kt + 1) << 10) + lane * 16;
            n0 = *(const short8*)(tn);
            n1 = *(const short8*)(tn + 8);
        }
        float* pd = p_out + ((size_t)h * NN + q0) * NN + kt * 64 + lane;
#pragma unroll
        for (int j = 0; j < 8; j++) pd[(size_t)j * NN] = bf2f(pv0[j]) * linvv[j];
#pragma unroll
        for (int j = 0; j < 8; j++) pd[(size_t)(8 + j) * NN] = bf2f(pv1[j]) * linvv[8 + j];
        pv0 = n0; pv1 = n1;
    }

    // ---- two-phase staggered cross-wave x1 reduce (reuses plds memory) ----
    __syncthreads();
    if (w >= 4) {
#pragma unroll
        for (int fd = 0; fd < 4; fd++)
#pragma unroll
            for (int r = 0; r < 4; r++) xbuf[w - 4][lane][fd * 4 + r] = acc1[fd][r];
    }
    __syncthreads();
    if (w < 4) {
#pragma unroll
        for (int fd = 0; fd < 4; fd++)
#pragma unroll
            for (int r = 0; r < 4; r++) acc1[fd][r] += xbuf[w][lane][fd * 4 + r];
    }
    __syncthreads();
    if (w >= 1 && w < 4) {
#pragma unroll
        for (int fd = 0; fd < 4; fd++)
#pragma unroll
            for (int r = 0; r < 4; r++) xbuf[w - 1][lane][fd * 4 + r] = acc1[fd][r];
    }
    __syncthreads();
    if (w == 0) {
#pragma unroll
        for (int fd = 0; fd < 4; fd++)
#pragma unroll
            for (int r = 0; r < 4; r++) {
                float v = acc1[fd][r] + xbuf[0][lane][fd * 4 + r] + xbuf[1][lane][fd * 4 + r] +
                          xbuf[2][lane][fd * 4 + r];
                v *= linv_s[lg * 4 + r];
                v = v > 0.f ? v : (__expf(v) - 1.f);
                x1_out[(size_t)(q0 + lg * 4 + r) * ODIM + h * DKH + fd * 16 + lr] = v;
            }
    }
}

// scale qv by linv along q: qvS[h][d][q] = qvT[h][d][q] * linv[h][q]
__global__ __launch_bounds__(256) void scale_qv_k(const short* __restrict__ qvT,
                                                  const float* __restrict__ linv,
                                                  short* __restrict__ qvS) {
    int idx = blockIdx.x * 256 + threadIdx.x;   // 131072 threads, short8 each
    int q8 = idx & 511;
    int dh = idx >> 9;                          // h*64 + d
    int h = dh >> 6;
    short8 v = *(const short8*)(qvT + (size_t)dh * NN + q8 * 8);
    const float* lp = linv + (size_t)h * NN + q8 * 8;
    float4 l0 = *(const float4*)lp;
    float4 l1 = *(const float4*)(lp + 4);
    short8 o;
    o[0] = f2bf(bf2f(v[0]) * l0.x); o[1] = f2bf(bf2f(v[1]) * l0.y);
    o[2] = f2bf(bf2f(v[2]) * l0.z); o[3] = f2bf(bf2f(v[3]) * l0.w);
    o[4] = f2bf(bf2f(v[4]) * l1.x); o[5] = f2bf(bf2f(v[5]) * l1.y);
    o[6] = f2bf(bf2f(v[6]) * l1.z); o[7] = f2bf(bf2f(v[7]) * l1.w);
    *(short8*)(qvS + (size_t)dh * NN + q8 * 8) = o;
}

// px2b v2: x2part[z] = p~^T @ qvS over q in [z*1024,(z+1)*1024).
// Waves = (kg key-half, sh q-quarter): each wave carries 2 A-frags (32 keys)
// and contracts 256 q in 8 its of {2 A + 4 B loads, 8 MFMAs}. B redundancy
// 2x (was 4x); serial length halved. Three-phase staggered sh-reduce.
__global__ __launch_bounds__(512) void px2b_k(
    const short* __restrict__ pbuf, const short* __restrict__ qvS,
    float* __restrict__ x2part) {
    int kt = blockIdx.x, h = blockIdx.y, z = blockIdx.z;
    int tid = threadIdx.x, lane = tid & 63, w = tid >> 6;
    int kg = w & 1, sh = w >> 1;
    int lr = lane & 15, lg = lane >> 4;

    __shared__ float red[4][64][33];   // 33,792 B

    const short* qvh = qvS + (size_t)h * DKH * NN;
    f32x4 acc[2][4] = {};
    int qz = z * 1024 + sh * 256;

#pragma unroll
    for (int it = 0; it < 8; it++) {
        int qq = qz + it * 32;
        int strip = (qq >> 4) + (lg >> 1);
        const short* tb = pbuf + (((size_t)(h * 256 + strip) * 64 + kt) << 10) + (lg & 1) * 8;
        short8 af0 = *(const short8*)(tb + (kg * 32 + lr) * 16);
        short8 af1 = *(const short8*)(tb + (kg * 32 + 16 + lr) * 16);
        short8 bv0 = *(const short8*)(qvh + (size_t)(0 * 16 + lr) * NN + qq + lg * 8);
        short8 bv1 = *(const short8*)(qvh + (size_t)(1 * 16 + lr) * NN + qq + lg * 8);
        short8 bv2 = *(const short8*)(qvh + (size_t)(2 * 16 + lr) * NN + qq + lg * 8);
        short8 bv3 = *(const short8*)(qvh + (size_t)(3 * 16 + lr) * NN + qq + lg * 8);
        acc[0][0] = mfma16(af0, bv0, acc[0][0]);
        acc[0][1] = mfma16(af0, bv1, acc[0][1]);
        acc[0][2] = mfma16(af0, bv2, acc[0][2]);
        acc[0][3] = mfma16(af0, bv3, acc[0][3]);
        acc[1][0] = mfma16(af1, bv0, acc[1][0]);
        acc[1][1] = mfma16(af1, bv1, acc[1][1]);
        acc[1][2] = mfma16(af1, bv2, acc[1][2]);
        acc[1][3] = mfma16(af1, bv3, acc[1][3]);
    }
    // ---- three-phase staggered reduce over sh (same kg) ----
    if (w >= 4) {
#pragma unroll
        for (int fj2 = 0; fj2 < 2; fj2++)
#pragma unroll
            for (int fd = 0; fd < 4; fd++)
#pragma unroll
                for (int r = 0; r < 4; r++)
                    red[w - 4][lane][fj2 * 16 + fd * 4 + r] = acc[fj2][fd][r];
    }
    __syncthreads();
    if (w < 4) {
#pragma unroll
        for (int fj2 = 0; fj2 < 2; fj2++)
#pragma unroll
            for (int fd = 0; fd < 4; fd++)
#pragma unroll
                for (int r = 0; r < 4; r++)
                    acc[fj2][fd][r] += red[w][lane][fj2 * 16 + fd * 4 + r];
    }
    __syncthreads();
    if (w >= 2 && w < 4) {
#pragma unroll
        for (int fj2 = 0; fj2 < 2; fj2++)
#pragma unroll
            for (int fd = 0; fd < 4; fd++)
#pragma unroll
                for (int r = 0; r < 4; r++)
                    red[w - 2][lane][fj2 * 16 + fd * 4 + r] = acc[fj2][fd][r];
    }
    __syncthreads();
    if (w < 2) {
        float* xp = x2part + (size_t)z * NN * ODIM;
#pragma unroll
        for (int fj2 = 0; fj2 < 2; fj2++)
#pragma unroll
            for (int fd = 0; fd < 4; fd++)
#pragma unroll
                for (int r = 0; r < 4; r++) {
                    float v = acc[fj2][fd][r] + red[w][lane][fj2 * 16 + fd * 4 + r];
                    int row = kt * 64 + kg * 32 + fj2 * 16 + lg * 4 + r;
                    xp[(size_t)row * ODIM + h * DKH + fd * 16 + lr] = v;
                }
    }
}

// combine: x2 = ELU(part0 + part1 + part2 + part3)
__global__ __launch_bounds__(256) void combine_x2_k(const float* __restrict__ x2part,
                                                    float* __restrict__ x2_out) {
    int idx = blockIdx.x * 256 + threadIdx.x;   // 262144 threads, float4 each
    size_t i = (size_t)idx * 4;
    const size_t stride = (size_t)NN * ODIM;
    float4 a = *(const float4*)(x2part + i);
    float4 b = *(const float4*)(x2part + stride + i);
    float4 c = *(const float4*)(x2part + 2 * stride + i);
    float4 d = *(const float4*)(x2part + 3 * stride + i);
    float4 o;
    o.x = a.x + b.x + c.x + d.x;
    o.y = a.y + b.y + c.y + d.y;
    o.z = a.z + b.z + c.z + d.z;
    o.w = a.w + b.w + c.w + d.w;
    o.x = o.x > 0.f ? o.x : (__expf(o.x) - 1.f);
    o.y = o.y > 0.f ? o.y : (__expf(o.y) - 1.f);
    o.z = o.z > 0.f ? o.z : (__expf(o.z) - 1.f);
    o.w = o.w > 0.f ? o.w : (__expf(o.w) - 1.f);
    *(float4*)(x2_out + i) = o;
}

// ================= FALLBACK PATH (known-good) =================
__global__ __launch_bounds__(512) void attn_fb_k(
    const short* __restrict__ qh, const short* __restrict__ kh, const short* __restrict__ kvT,
    const unsigned long long* __restrict__ bits,
    float* __restrict__ x1_out, float* __restrict__ p_out) {
    int h = blockIdx.y;
    int tid = threadIdx.x, lane = tid & 63, w = tid >> 6;
    int lr = lane & 15, lg = lane >> 4;
    int q0 = blockIdx.x * 16;

    __shared__ float smemf[4608];
    short (*plds)[16][72] = (short (*)[16][72])smemf;
    float (*xbuf)[64][17] = (float (*)[64][17])smemf;
    __shared__ float sl[8][16];

    const short* khh = kh + (size_t)h * NN * DKH;
    const unsigned long long* brow = bits + (size_t)(q0 + lr) * NKW;

    short8 bq[2];
#pragma unroll
    for (int kk = 0; kk < 2; kk++)
        bq[kk] = *(const short8*)(qh + ((size_t)h * NN + q0 + lr) * DKH + kk * 32 + lg * 8);

    float lrun = 0.f;
    for (int t = 0; t < 8; t++) {
        int kt = w * 8 + t;
        f32x4 s[4] = {};
#pragma unroll
        for (int fj = 0; fj < 4; fj++)
#pragma unroll
            for (int kk = 0; kk < 2; kk++) {
                short8 a = *(const short8*)(khh + (size_t)(kt * 64 + fj * 16 + lr) * DKH + kk * 32 + lg * 8);
                s[fj] = mfma16(a, bq[kk], s[fj]);
            }
        unsigned long long mw = brow[kt] >> (lg * 4);
#pragma unroll
        for (int fj = 0; fj < 4; fj++)
#pragma unroll
            for (int r = 0; r < 4; r++) {
                bool keep = (mw >> (fj * 16 + r)) & 1ull;
                lrun += __expf(keep ? s[fj][r] : -100.f);
            }
    }
    lrun += __shfl_xor(lrun, 16);
    lrun += __shfl_xor(lrun, 32);
    if (lg == 0) sl[w][lr] = lrun;
    __syncthreads();
    float l = 0.f;
#pragma unroll
    for (int w2 = 0; w2 < 8; w2++) l += sl[w2][lr];
    float linv = l > 0.f ? 1.f / l : 0.f;

    f32x4 acc1[4] = {};
    float* prow = p_out + ((size_t)h * NN + q0 + lr) * NN;
    for (int t = 0; t < 8; t++) {
        int kt = w * 8 + t;
        f32x4 s[4] = {};
#pragma unroll
        for (int fj = 0; fj < 4; fj++)
#pragma unroll
            for (int kk = 0; kk < 2; kk++) {
                short8 a = *(const short8*)(khh + (size_t)(kt * 64 + fj * 16 + lr) * DKH + kk * 32 + lg * 8);
                s[fj] = mfma16(a, bq[kk], s[fj]);
            }
        unsigned long long mw = brow[kt] >> (lg * 4);
#pragma unroll
        for (int fj = 0; fj < 4; fj++) {
            float4 pv;
            short4v pb;
#pragma unroll
            for (int r = 0; r < 4; r++) {
                bool keep = (mw >> (fj * 16 + r)) & 1ull;
                float p = __expf(keep ? s[fj][r] : -100.f) * linv;
                (&pv.x)[r] = p;
                pb[r] = f2bf(p);
            }
            *(float4*)(prow + kt * 64 + fj * 16 + lg * 4) = pv;
            *(short4v*)&plds[w][lr][fj * 16 + lg * 4] = pb;
        }
#pragma unroll
        for (int kk = 0; kk < 2; kk++) {
            short8 a1 = *(const short8*)&plds[w][lr][kk * 32 + lg * 8];
#pragma unroll
            for (int fd = 0; fd < 4; fd++) {
                short8 bv = *(const short8*)(kvT + ((size_t)h * DKH + fd * 16 + lr) * NN + kt * 64 + kk * 32 + lg * 8);
                acc1[fd] = mfma16(a1, bv, acc1[fd]);
            }
        }
    }
    __syncthreads();
    if (w >= 4) {
#pragma unroll
        for (int fd = 0; fd < 4; fd++)
#pragma unroll
            for (int r = 0; r < 4; r++) xbuf[w - 4][lane][fd * 4 + r] = acc1[fd][r];
    }
    __syncthreads();
    if (w < 4) {
#pragma unroll
        for (int fd = 0; fd < 4; fd++)
#pragma unroll
            for (int r = 0; r < 4; r++) acc1[fd][r] += xbuf[w][lane][fd * 4 + r];
    }
    __syncthreads();
    if (w >= 1 && w < 4) {
#pragma unroll
        for (int fd = 0; fd < 4; fd++)
#pragma unroll
            for (int r = 0; r < 4; r++) xbuf[w - 1][lane][fd * 4 + r] = acc1[fd][r];
    }
    __syncthreads();
    if (w == 0) {
#pragma unroll
        for (int fd = 0; fd < 4; fd++)
#pragma unroll
            for (int r = 0; r < 4; r++) {
                float v = acc1[fd][r] + xbuf[0][lane][fd * 4 + r] + xbuf[1][lane][fd * 4 + r] +
                          xbuf[2][lane][fd * 4 + r];
                v = v > 0.f ? v : (__expf(v) - 1.f);
                x1_out[(size_t)(q0 + lg * 4 + r) * ODIM + h * DKH + fd * 16 + lr] = v;
            }
    }
}

__global__ __launch_bounds__(512) void px2_fb_k(
    const float* __restrict__ p, const short* __restrict__ qvT,
    float* __restrict__ x2_out) {
    int h = blockIdx.y;
    int k0 = blockIdx.x * 32;
    int tid = threadIdx.x, lane = tid & 63, w = tid >> 6;
    int lr = lane & 15, lg = lane >> 4;

    __shared__ float red[4][64][33];

    f32x4 acc[2][4] = {};
    const float* pbase = p + (size_t)h * NN * NN;
    const short* qvh = qvT + (size_t)h * DKH * NN;

    for (int it = 0; it < 16; it++) {
        int qq = w * 512 + it * 32;
        short8 aP[2];
#pragma unroll
        for (int fj = 0; fj < 2; fj++) {
            const float* pp = pbase + (size_t)(qq + lg * 8) * NN + k0 + fj * 16 + lr;
            short8 av;
#pragma unroll
            for (int j = 0; j < 8; j++) av[j] = f2bf(pp[j * NN]);
            aP[fj] = av;
        }
#pragma unroll
        for (int fd = 0; fd < 4; fd++) {
            short8 bv = *(const short8*)(qvh + (size_t)(fd * 16 + lr) * NN + qq + lg * 8);
#pragma unroll
            for (int fj = 0; fj < 2; fj++) acc[fj][fd] = mfma16(aP[fj], bv, acc[fj][fd]);
        }
    }
    if (w >= 4) {
#pragma unroll
        for (int fj = 0; fj < 2; fj++)
#pragma unroll
            for (int fd = 0; fd < 4; fd++)
#pragma unroll
                for (int r = 0; r < 4; r++)
                    red[w - 4][lane][fj * 16 + fd * 4 + r] = acc[fj][fd][r];
    }
    __syncthreads();
    if (w < 4) {
#pragma unroll
        for (int fj = 0; fj < 2; fj++)
#pragma unroll
            for (int fd = 0; fd < 4; fd++)
#pragma unroll
                for (int r = 0; r < 4; r++)
                    acc[fj][fd][r] += red[w][lane][fj * 16 + fd * 4 + r];
    }
    __syncthreads();
    if (w >= 1 && w < 4) {
#pragma unroll
        for (int fj = 0; fj < 2; fj++)
#pragma unroll
            for (int fd = 0; fd < 4; fd++)
#pragma unroll
                for (int r = 0; r < 4; r++)
                    red[w - 1][lane][fj * 16 + fd * 4 + r] = acc[fj][fd][r];
    }
    __syncthreads();
    if (w == 0) {
#pragma unroll
        for (int fj = 0; fj < 2; fj++)
#pragma unroll
            for (int fd = 0; fd < 4; fd++)
#pragma unroll
                for (int r = 0; r < 4; r++) {
                    float v = acc[fj][fd][r];
#pragma unroll
                    for (int s2 = 0; s2 < 3; s2++) v += red[s2][lane][fj * 16 + fd * 4 + r];
                    v = v > 0.f ? v : (__expf(v) - 1.f);
                    x2_out[(size_t)(k0 + fj * 16 + lg * 4 + r) * ODIM + h * DKH + fd * 16 + lr] = v;
                }
    }
}

extern "C" void kernel_launch(void* const* d_in, const int* in_sizes, int n_in,
                              void* d_out, int out_size, void* d_ws, size_t ws_size,
                              hipStream_t stream) {
    (void)in_sizes; (void)n_in; (void)out_size;
    const float* query = (const float*)d_in[0];
    const float* key   = (const float*)d_in[1];
    const int*   mask  = (const int*)d_in[2];
    const float* Wq  = (const float*)d_in[3];
    const float* bq  = (const float*)d_in[4];
    const float* Wk  = (const float*)d_in[5];
    const float* bk  = (const float*)d_in[6];
    const float* Wqv = (const float*)d_in[7];
    const float* bqv = (const float*)d_in[8];
    const float* Wkv = (const float*)d_in[9];
    const float* bkv = (const float*)d_in[10];

    float* out = (float*)d_out;
    float* x1 = out;
    float* x2 = out + (size_t)NN * ODIM;
    float* p  = out + (size_t)2 * NN * ODIM;

    char* ws = (char*)d_ws;
    short* qh  = (short*)(ws);
    short* kh  = (short*)(ws + (2ull << 20));
    short* qvT = (short*)(ws + (4ull << 20));
    short* kvT = (short*)(ws + (6ull << 20));
    unsigned long long* bits = (unsigned long long*)(ws + (8ull << 20));
    float* linv_ws = (float*)(ws + (10ull << 20));
    short* qvS = (short*)(ws + (10ull << 20) + (1ull << 19));
    float* x2part = (float*)(ws + (13ull << 20));            // 4 x 4 MB
    short* pbuf = (short*)(ws + (29ull << 20));               // 128 MB
    size_t need = (29ull << 20) + (size_t)NHEAD * NN * NN * sizeof(short);

    hipLaunchKernelGGL(pack_mask_k, dim3(NN * NN / 64 / 4), dim3(256), 0, stream, mask, bits);
    hipLaunchKernelGGL(proj_k, dim3(64, 4, 4), dim3(256), 0, stream,
                       query, key, Wq, bq, Wk, bk, Wqv, bqv, Wkv, bkv, qh, kh, qvT, kvT);

    if (ws_size >= need) {
        hipLaunchKernelGGL(attn_fused_k, dim3(NN / 16, NHEAD), dim3(512), 0, stream,
                           qh, kh, kvT, bits, pbuf, linv_ws, x1, p);
        hipLaunchKernelGGL(scale_qv_k, dim3(512), dim3(256), 0, stream, qvT, linv_ws, qvS);
        hipLaunchKernelGGL(px2b_k, dim3(NN / 64, NHEAD, 4), dim3(512), 0, stream,
                           pbuf, qvS, x2part);
        hipLaunchKernelGGL(combine_x2_k, dim3(NN * ODIM / 4 / 256), dim3(256), 0, stream,
                           x2part, x2);
    } else {
        hipLaunchKernelGGL(attn_fb_k, dim3(NN / 16, NHEAD), dim3(512), 0, stream,
                           qh, kh, kvT, bits, x1, p);
        hipLaunchKernelGGL(px2_fb_k, dim3(NN / 32, NHEAD), dim3(512), 0, stream,
                           p, qvT, x2);
    }
}

// Round 13
// 321.549 us; speedup vs baseline: 1.4960x; 1.0096x over previous
//
#include <hip/hip_runtime.h>
#include <hip/hip_bf16.h>

#define NN 4096
#define DMODEL 512
#define ODIM 256
#define NHEAD 4
#define DKH 64
#define NKW 64  // NN/64 mask words per row

typedef __attribute__((ext_vector_type(8))) short short8;
typedef __attribute__((ext_vector_type(4))) short short4v;
typedef __attribute__((ext_vector_type(8))) __bf16 bf16x8;
typedef __attribute__((ext_vector_type(4))) float f32x4;

__device__ __forceinline__ short f2bf(float f) {
    unsigned u = __builtin_bit_cast(unsigned, f);
    u += 0x7fffu + ((u >> 16) & 1u);   // RNE (no NaN in this data)
    return (short)(u >> 16);
}
__device__ __forceinline__ float bf2f(short s) {
    unsigned u = ((unsigned)(unsigned short)s) << 16;
    return __builtin_bit_cast(float, u);
}
__device__ __forceinline__ f32x4 mfma16(short8 a, short8 b, f32x4 c) {
    return __builtin_amdgcn_mfma_f32_16x16x32_bf16(
        __builtin_bit_cast(bf16x8, a), __builtin_bit_cast(bf16x8, b), c, 0, 0, 0);
}

// ---------------- mask int32 -> bitmask (1 = keep) ----------------
__global__ __launch_bounds__(256) void pack_mask_k(const int* __restrict__ mask,
                                                   unsigned long long* __restrict__ bits) {
    int tid = blockIdx.x * 256 + threadIdx.x;
    int wid = tid >> 6;
    int lane = tid & 63;
    int v = __builtin_nontemporal_load(mask + (size_t)wid * 64 + lane);
    unsigned long long b = __ballot(v != 0);
    if (lane == 0) bits[wid] = b;
}

// ---------------- 4 projections: Y = X @ W^T + b, bf16 out ----------------
// tr=0 (qh, kh): acc = mfma(X_frag, W_frag) -> [q][out_dim], 32B-run stores.
// tr=1 (qvT, kvT): acc = mfma(W_frag, X_frag) -> accumulator already in
// [out_dim][q] orientation -> 32B-run stores too (no LDS, no transpose).
__global__ __launch_bounds__(256) void proj_k(
    const float* __restrict__ Xq, const float* __restrict__ Xk,
    const float* __restrict__ Wq, const float* __restrict__ bq,
    const float* __restrict__ Wk, const float* __restrict__ bk,
    const float* __restrict__ Wqv, const float* __restrict__ bqv,
    const float* __restrict__ Wkv, const float* __restrict__ bkv,
    short* __restrict__ qh, short* __restrict__ kh,
    short* __restrict__ qvT, short* __restrict__ kvT) {
    int z = blockIdx.z;
    const float *X, *W, *B;
    short* out;
    int tr;
    float postscale = 1.f;
    switch (z) {
        case 0: X = Xq; W = Wq;  B = bq;  out = qh;  tr = 0; postscale = 0.125f; break;
        case 1: X = Xk; W = Wk;  B = bk;  out = kh;  tr = 0; break;
        case 2: X = Xq; W = Wqv; B = bqv; out = qvT; tr = 1; break;
        default: X = Xk; W = Wkv; B = bkv; out = kvT; tr = 1; break;
    }
    int lane = threadIdx.x & 63, w = threadIdx.x >> 6;
    int lr = lane & 15, lg = lane >> 4;
    int m0 = blockIdx.x * 64 + (w >> 1) * 32;
    int n0 = blockIdx.y * 64 + (w & 1) * 32;

    f32x4 acc[2][2] = {};
    for (int kk = 0; kk < DMODEL; kk += 32) {
        short8 a[2], b[2];
#pragma unroll
        for (int i = 0; i < 2; i++) {
            const float* pa = X + (size_t)(m0 + i * 16 + lr) * DMODEL + kk + lg * 8;
            const float* pb = W + (size_t)(n0 + i * 16 + lr) * DMODEL + kk + lg * 8;
            float4 a0 = *(const float4*)pa;
            float4 a1 = *(const float4*)(pa + 4);
            float4 b0 = *(const float4*)pb;
            float4 b1 = *(const float4*)(pb + 4);
            a[i][0] = f2bf(a0.x); a[i][1] = f2bf(a0.y); a[i][2] = f2bf(a0.z); a[i][3] = f2bf(a0.w);
            a[i][4] = f2bf(a1.x); a[i][5] = f2bf(a1.y); a[i][6] = f2bf(a1.z); a[i][7] = f2bf(a1.w);
            b[i][0] = f2bf(b0.x); b[i][1] = f2bf(b0.y); b[i][2] = f2bf(b0.z); b[i][3] = f2bf(b0.w);
            b[i][4] = f2bf(b1.x); b[i][5] = f2bf(b1.y); b[i][6] = f2bf(b1.z); b[i][7] = f2bf(b1.w);
        }
        if (!tr) {
#pragma unroll
            for (int i = 0; i < 2; i++)
#pragma unroll
                for (int j = 0; j < 2; j++) acc[i][j] = mfma16(a[i], b[j], acc[i][j]);
        } else {
#pragma unroll
            for (int i = 0; i < 2; i++)
#pragma unroll
                for (int j = 0; j < 2; j++) acc[i][j] = mfma16(b[j], a[i], acc[i][j]);
        }
    }
    if (!tr) {
        // acc[i][j]: row(q) = m0+i*16+lg*4+r, col(out_dim) = n0+j*16+lr
#pragma unroll
        for (int i = 0; i < 2; i++)
#pragma unroll
            for (int j = 0; j < 2; j++) {
                int col = n0 + j * 16 + lr;
                float bv = B[col];
                int hh = col >> 6, dk = col & 63;
#pragma unroll
                for (int r = 0; r < 4; r++) {
                    int row = m0 + i * 16 + lg * 4 + r;
                    short s = f2bf((acc[i][j][r] + bv) * postscale);
                    out[((size_t)hh * NN + row) * DKH + dk] = s;
                }
            }
    } else {
        // acc[i][j]: row(out_dim) = n0+j*16+lg*4+r, col(q) = m0+i*16+lr
#pragma unroll
        for (int i = 0; i < 2; i++)
#pragma unroll
            for (int j = 0; j < 2; j++) {
                float4 bv4 = *(const float4*)(B + n0 + j * 16 + lg * 4);
                int qrow = m0 + i * 16 + lr;
#pragma unroll
                for (int r = 0; r < 4; r++) {
                    int colw = n0 + j * 16 + lg * 4 + r;
                    int hh = colw >> 6, dk = colw & 63;
                    short s = f2bf(acc[i][j][r] + (&bv4.x)[r]);
                    out[((size_t)hh * DKH + dk) * NN + qrow] = s;
                }
            }
    }
}

// ================= PRIMARY PATH =================
// Kernel A (R10/R12, known-good): single sweep, key-major pbuf via LDS
// transpose, denom + x1, double-buffered normalize tail.
__global__ __launch_bounds__(512) void attn_fused_k(
    const short* __restrict__ qh, const short* __restrict__ kh, const short* __restrict__ kvT,
    const unsigned long long* __restrict__ bits,
    short* __restrict__ pbuf, float* __restrict__ linv_ws,
    float* __restrict__ x1_out, float* __restrict__ p_out) {
    int h = blockIdx.y;
    int strip = blockIdx.x;
    int tid = threadIdx.x, lane = tid & 63, w = tid >> 6;  // w in 0..7
    int lr = lane & 15, lg = lane >> 4;
    int q0 = strip * 16;

    __shared__ float smemf[4608];                       // 18 KB union
    short (*plds)[16][72] = (short (*)[16][72])smemf;   // [8][16][72] bf16
    float (*xbuf)[64][17] = (float (*)[64][17])smemf;   // [4][64][17] f32
    __shared__ float sl[8][16];
    __shared__ float linv_s[16];

    const short* khh = kh + (size_t)h * NN * DKH;
    const unsigned long long* brow = bits + (size_t)(q0 + lr) * NKW;
    short* ptile0 = pbuf + (((size_t)(h * 256 + strip) * 64) << 10);

    short8 bq[2];
#pragma unroll
    for (int kk = 0; kk < 2; kk++)
        bq[kk] = *(const short8*)(qh + ((size_t)h * NN + q0 + lr) * DKH + kk * 32 + lg * 8);

    float lrun = 0.f;
    f32x4 acc1[4] = {};
    for (int t = 0; t < 8; t++) {
        int kt = w * 8 + t;
        f32x4 s[4] = {};
#pragma unroll
        for (int fj = 0; fj < 4; fj++)
#pragma unroll
            for (int kk = 0; kk < 2; kk++) {
                short8 a = *(const short8*)(khh + (size_t)(kt * 64 + fj * 16 + lr) * DKH + kk * 32 + lg * 8);
                s[fj] = mfma16(a, bq[kk], s[fj]);
            }
        unsigned long long mw = brow[kt] >> (lg * 4);
#pragma unroll
        for (int fj = 0; fj < 4; fj++) {
            short4v pb4;
#pragma unroll
            for (int r = 0; r < 4; r++) {
                bool keep = (mw >> (fj * 16 + r)) & 1ull;
                float e = __expf(keep ? s[fj][r] : -100.f);
                lrun += e;
                pb4[r] = f2bf(e);
            }
            *(short4v*)&plds[w][lr][fj * 16 + lg * 4] = pb4;
        }
        // x1 += p~ @ kv (wave-private LDS strip; loads before the pbuf stores)
#pragma unroll
        for (int kk = 0; kk < 2; kk++) {
            short8 a1 = *(const short8*)&plds[w][lr][kk * 32 + lg * 8];
#pragma unroll
            for (int fd = 0; fd < 4; fd++) {
                short8 bv = *(const short8*)(kvT + ((size_t)h * DKH + fd * 16 + lr) * NN + kt * 64 + kk * 32 + lg * 8);
                acc1[fd] = mfma16(a1, bv, acc1[fd]);
            }
        }
        // pbuf tile write via LDS transpose: lane = key, 2 x 16B stores
        {
            short8 v0, v1;
#pragma unroll
            for (int j = 0; j < 8; j++) v0[j] = plds[w][j][lane];
#pragma unroll
            for (int j = 0; j < 8; j++) v1[j] = plds[w][8 + j][lane];
            short* ptile = ptile0 + ((size_t)kt << 10) + lane * 16;
            *(short8*)(ptile) = v0;
            *(short8*)(ptile + 8) = v1;
        }
    }
    // ---- denominator reduce ----
    lrun += __shfl_xor(lrun, 16);
    lrun += __shfl_xor(lrun, 32);
    if (lg == 0) sl[w][lr] = lrun;
    __syncthreads();
    float l = 0.f;
#pragma unroll
    for (int w2 = 0; w2 < 8; w2++) l += sl[w2][lr];
    float linv = l > 0.f ? 1.f / l : 0.f;
    if (w == 0 && lg == 0) {
        linv_s[lr] = linv;
        linv_ws[(size_t)h * NN + q0 + lr] = linv;
    }
    __syncthreads();

    // ---- streaming tail: normalize own tiles -> f32 p (double-buffered) ----
    asm volatile("s_waitcnt vmcnt(0)" ::: "memory");
    float linvv[16];
#pragma unroll
    for (int j = 0; j < 16; j++) linvv[j] = linv_s[j];
    const short* tl0 = ptile0 + ((size_t)(w * 8) << 10) + lane * 16;
    short8 pv0 = *(const short8*)(tl0);
    short8 pv1 = *(const short8*)(tl0 + 8);
    for (int t = 0; t < 8; t++) {
        int kt = w * 8 + t;
        short8 n0 = pv0, n1 = pv1;
        if (t < 7) {
            const short* tn = ptile0 + ((size_t)(kt + 1) << 10) + lane * 16;
            n0 = *(const short8*)(tn);
            n1 = *(const short8*)(tn + 8);
        }
        float* pd = p_out + ((size_t)h * NN + q0) * NN + kt * 64 + lane;
#pragma unroll
        for (int j = 0; j < 8; j++) pd[(size_t)j * NN] = bf2f(pv0[j]) * linvv[j];
#pragma unroll
        for (int j = 0; j < 8; j++) pd[(size_t)(8 + j) * NN] = bf2f(pv1[j]) * linvv[8 + j];
        pv0 = n0; pv1 = n1;
    }

    // ---- two-phase staggered cross-wave x1 reduce (reuses plds memory) ----
    __syncthreads();
    if (w >= 4) {
#pragma unroll
        for (int fd = 0; fd < 4; fd++)
#pragma unroll
            for (int r = 0; r < 4; r++) xbuf[w - 4][lane][fd * 4 + r] = acc1[fd][r];
    }
    __syncthreads();
    if (w < 4) {
#pragma unroll
        for (int fd = 0; fd < 4; fd++)
#pragma unroll
            for (int r = 0; r < 4; r++) acc1[fd][r] += xbuf[w][lane][fd * 4 + r];
    }
    __syncthreads();
    if (w >= 1 && w < 4) {
#pragma unroll
        for (int fd = 0; fd < 4; fd++)
#pragma unroll
            for (int r = 0; r < 4; r++) xbuf[w - 1][lane][fd * 4 + r] = acc1[fd][r];
    }
    __syncthreads();
    if (w == 0) {
#pragma unroll
        for (int fd = 0; fd < 4; fd++)
#pragma unroll
            for (int r = 0; r < 4; r++) {
                float v = acc1[fd][r] + xbuf[0][lane][fd * 4 + r] + xbuf[1][lane][fd * 4 + r] +
                          xbuf[2][lane][fd * 4 + r];
                v *= linv_s[lg * 4 + r];
                v = v > 0.f ? v : (__expf(v) - 1.f);
                x1_out[(size_t)(q0 + lg * 4 + r) * ODIM + h * DKH + fd * 16 + lr] = v;
            }
    }
}

// scale qv by linv along q: qvS[h][d][q] = qvT[h][d][q] * linv[h][q]
__global__ __launch_bounds__(256) void scale_qv_k(const short* __restrict__ qvT,
                                                  const float* __restrict__ linv,
                                                  short* __restrict__ qvS) {
    int idx = blockIdx.x * 256 + threadIdx.x;   // 131072 threads, short8 each
    int q8 = idx & 511;
    int dh = idx >> 9;                          // h*64 + d
    int h = dh >> 6;
    short8 v = *(const short8*)(qvT + (size_t)dh * NN + q8 * 8);
    const float* lp = linv + (size_t)h * NN + q8 * 8;
    float4 l0 = *(const float4*)lp;
    float4 l1 = *(const float4*)(lp + 4);
    short8 o;
    o[0] = f2bf(bf2f(v[0]) * l0.x); o[1] = f2bf(bf2f(v[1]) * l0.y);
    o[2] = f2bf(bf2f(v[2]) * l0.z); o[3] = f2bf(bf2f(v[3]) * l0.w);
    o[4] = f2bf(bf2f(v[4]) * l1.x); o[5] = f2bf(bf2f(v[5]) * l1.y);
    o[6] = f2bf(bf2f(v[6]) * l1.z); o[7] = f2bf(bf2f(v[7]) * l1.w);
    *(short8*)(qvS + (size_t)dh * NN + q8 * 8) = o;
}

// px2b v2: x2part[z] = p~^T @ qvS over q in [z*1024,(z+1)*1024).
// Waves = (kg key-half, sh q-quarter): each wave carries 2 A-frags (32 keys)
// and contracts 256 q in 8 its of {2 A + 4 B loads, 8 MFMAs}.
__global__ __launch_bounds__(512) void px2b_k(
    const short* __restrict__ pbuf, const short* __restrict__ qvS,
    float* __restrict__ x2part) {
    int kt = blockIdx.x, h = blockIdx.y, z = blockIdx.z;
    int tid = threadIdx.x, lane = tid & 63, w = tid >> 6;
    int kg = w & 1, sh = w >> 1;
    int lr = lane & 15, lg = lane >> 4;

    __shared__ float red[4][64][33];   // 33,792 B

    const short* qvh = qvS + (size_t)h * DKH * NN;
    f32x4 acc[2][4] = {};
    int qz = z * 1024 + sh * 256;

#pragma unroll
    for (int it = 0; it < 8; it++) {
        int qq = qz + it * 32;
        int strip = (qq >> 4) + (lg >> 1);
        const short* tb = pbuf + (((size_t)(h * 256 + strip) * 64 + kt) << 10) + (lg & 1) * 8;
        short8 af0 = *(const short8*)(tb + (kg * 32 + lr) * 16);
        short8 af1 = *(const short8*)(tb + (kg * 32 + 16 + lr) * 16);
        short8 bv0 = *(const short8*)(qvh + (size_t)(0 * 16 + lr) * NN + qq + lg * 8);
        short8 bv1 = *(const short8*)(qvh + (size_t)(1 * 16 + lr) * NN + qq + lg * 8);
        short8 bv2 = *(const short8*)(qvh + (size_t)(2 * 16 + lr) * NN + qq + lg * 8);
        short8 bv3 = *(const short8*)(qvh + (size_t)(3 * 16 + lr) * NN + qq + lg * 8);
        acc[0][0] = mfma16(af0, bv0, acc[0][0]);
        acc[0][1] = mfma16(af0, bv1, acc[0][1]);
        acc[0][2] = mfma16(af0, bv2, acc[0][2]);
        acc[0][3] = mfma16(af0, bv3, acc[0][3]);
        acc[1][0] = mfma16(af1, bv0, acc[1][0]);
        acc[1][1] = mfma16(af1, bv1, acc[1][1]);
        acc[1][2] = mfma16(af1, bv2, acc[1][2]);
        acc[1][3] = mfma16(af1, bv3, acc[1][3]);
    }
    // ---- three-phase staggered reduce over sh (same kg) ----
    if (w >= 4) {
#pragma unroll
        for (int fj2 = 0; fj2 < 2; fj2++)
#pragma unroll
            for (int fd = 0; fd < 4; fd++)
#pragma unroll
                for (int r = 0; r < 4; r++)
                    red[w - 4][lane][fj2 * 16 + fd * 4 + r] = acc[fj2][fd][r];
    }
    __syncthreads();
    if (w < 4) {
#pragma unroll
        for (int fj2 = 0; fj2 < 2; fj2++)
#pragma unroll
            for (int fd = 0; fd < 4; fd++)
#pragma unroll
                for (int r = 0; r < 4; r++)
                    acc[fj2][fd][r] += red[w][lane][fj2 * 16 + fd * 4 + r];
    }
    __syncthreads();
    if (w >= 2 && w < 4) {
#pragma unroll
        for (int fj2 = 0; fj2 < 2; fj2++)
#pragma unroll
            for (int fd = 0; fd < 4; fd++)
#pragma unroll
                for (int r = 0; r < 4; r++)
                    red[w - 2][lane][fj2 * 16 + fd * 4 + r] = acc[fj2][fd][r];
    }
    __syncthreads();
    if (w < 2) {
        float* xp = x2part + (size_t)z * NN * ODIM;
#pragma unroll
        for (int fj2 = 0; fj2 < 2; fj2++)
#pragma unroll
            for (int fd = 0; fd < 4; fd++)
#pragma unroll
                for (int r = 0; r < 4; r++) {
                    float v = acc[fj2][fd][r] + red[w][lane][fj2 * 16 + fd * 4 + r];
                    int row = kt * 64 + kg * 32 + fj2 * 16 + lg * 4 + r;
                    xp[(size_t)row * ODIM + h * DKH + fd * 16 + lr] = v;
                }
    }
}

// combine: x2 = ELU(part0 + part1 + part2 + part3)
__global__ __launch_bounds__(256) void combine_x2_k(const float* __restrict__ x2part,
                                                    float* __restrict__ x2_out) {
    int idx = blockIdx.x * 256 + threadIdx.x;   // 262144 threads, float4 each
    size_t i = (size_t)idx * 4;
    const size_t stride = (size_t)NN * ODIM;
    float4 a = *(const float4*)(x2part + i);
    float4 b = *(const float4*)(x2part + stride + i);
    float4 c = *(const float4*)(x2part + 2 * stride + i);
    float4 d = *(const float4*)(x2part + 3 * stride + i);
    float4 o;
    o.x = a.x + b.x + c.x + d.x;
    o.y = a.y + b.y + c.y + d.y;
    o.z = a.z + b.z + c.z + d.z;
    o.w = a.w + b.w + c.w + d.w;
    o.x = o.x > 0.f ? o.x : (__expf(o.x) - 1.f);
    o.y = o.y > 0.f ? o.y : (__expf(o.y) - 1.f);
    o.z = o.z > 0.f ? o.z : (__expf(o.z) - 1.f);
    o.w = o.w > 0.f ? o.w : (__expf(o.w) - 1.f);
    *(float4*)(x2_out + i) = o;
}

// ================= FALLBACK PATH (known-good) =================
__global__ __launch_bounds__(512) void attn_fb_k(
    const short* __restrict__ qh, const short* __restrict__ kh, const short* __restrict__ kvT,
    const unsigned long long* __restrict__ bits,
    float* __restrict__ x1_out, float* __restrict__ p_out) {
    int h = blockIdx.y;
    int tid = threadIdx.x, lane = tid & 63, w = tid >> 6;
    int lr = lane & 15, lg = lane >> 4;
    int q0 = blockIdx.x * 16;

    __shared__ float smemf[4608];
    short (*plds)[16][72] = (short (*)[16][72])smemf;
    float (*xbuf)[64][17] = (float (*)[64][17])smemf;
    __shared__ float sl[8][16];

    const short* khh = kh + (size_t)h * NN * DKH;
    const unsigned long long* brow = bits + (size_t)(q0 + lr) * NKW;

    short8 bq[2];
#pragma unroll
    for (int kk = 0; kk < 2; kk++)
        bq[kk] = *(const short8*)(qh + ((size_t)h * NN + q0 + lr) * DKH + kk * 32 + lg * 8);

    float lrun = 0.f;
    for (int t = 0; t < 8; t++) {
        int kt = w * 8 + t;
        f32x4 s[4] = {};
#pragma unroll
        for (int fj = 0; fj < 4; fj++)
#pragma unroll
            for (int kk = 0; kk < 2; kk++) {
                short8 a = *(const short8*)(khh + (size_t)(kt * 64 + fj * 16 + lr) * DKH + kk * 32 + lg * 8);
                s[fj] = mfma16(a, bq[kk], s[fj]);
            }
        unsigned long long mw = brow[kt] >> (lg * 4);
#pragma unroll
        for (int fj = 0; fj < 4; fj++)
#pragma unroll
            for (int r = 0; r < 4; r++) {
                bool keep = (mw >> (fj * 16 + r)) & 1ull;
                lrun += __expf(keep ? s[fj][r] : -100.f);
            }
    }
    lrun += __shfl_xor(lrun, 16);
    lrun += __shfl_xor(lrun, 32);
    if (lg == 0) sl[w][lr] = lrun;
    __syncthreads();
    float l = 0.f;
#pragma unroll
    for (int w2 = 0; w2 < 8; w2++) l += sl[w2][lr];
    float linv = l > 0.f ? 1.f / l : 0.f;

    f32x4 acc1[4] = {};
    float* prow = p_out + ((size_t)h * NN + q0 + lr) * NN;
    for (int t = 0; t < 8; t++) {
        int kt = w * 8 + t;
        f32x4 s[4] = {};
#pragma unroll
        for (int fj = 0; fj < 4; fj++)
#pragma unroll
            for (int kk = 0; kk < 2; kk++) {
                short8 a = *(const short8*)(khh + (size_t)(kt * 64 + fj * 16 + lr) * DKH + kk * 32 + lg * 8);
                s[fj] = mfma16(a, bq[kk], s[fj]);
            }
        unsigned long long mw = brow[kt] >> (lg * 4);
#pragma unroll
        for (int fj = 0; fj < 4; fj++) {
            float4 pv;
            short4v pb;
#pragma unroll
            for (int r = 0; r < 4; r++) {
                bool keep = (mw >> (fj * 16 + r)) & 1ull;
                float p = __expf(keep ? s[fj][r] : -100.f) * linv;
                (&pv.x)[r] = p;
                pb[r] = f2bf(p);
            }
            *(float4*)(prow + kt * 64 + fj * 16 + lg * 4) = pv;
            *(short4v*)&plds[w][lr][fj * 16 + lg * 4] = pb;
        }
#pragma unroll
        for (int kk = 0; kk < 2; kk++) {
            short8 a1 = *(const short8*)&plds[w][lr][kk * 32 + lg * 8];
#pragma unroll
            for (int fd = 0; fd < 4; fd++) {
                short8 bv = *(const short8*)(kvT + ((size_t)h * DKH + fd * 16 + lr) * NN + kt * 64 + kk * 32 + lg * 8);
                acc1[fd] = mfma16(a1, bv, acc1[fd]);
            }
        }
    }
    __syncthreads();
    if (w >= 4) {
#pragma unroll
        for (int fd = 0; fd < 4; fd++)
#pragma unroll
            for (int r = 0; r < 4; r++) xbuf[w - 4][lane][fd * 4 + r] = acc1[fd][r];
    }
    __syncthreads();
    if (w < 4) {
#pragma unroll
        for (int fd = 0; fd < 4; fd++)
#pragma unroll
            for (int r = 0; r < 4; r++) acc1[fd][r] += xbuf[w][lane][fd * 4 + r];
    }
    __syncthreads();
    if (w >= 1 && w < 4) {
#pragma unroll
        for (int fd = 0; fd < 4; fd++)
#pragma unroll
            for (int r = 0; r < 4; r++) xbuf[w - 1][lane][fd * 4 + r] = acc1[fd][r];
    }
    __syncthreads();
    if (w == 0) {
#pragma unroll
        for (int fd = 0; fd < 4; fd++)
#pragma unroll
            for (int r = 0; r < 4; r++) {
                float v = acc1[fd][r] + xbuf[0][lane][fd * 4 + r] + xbuf[1][lane][fd * 4 + r] +
                          xbuf[2][lane][fd * 4 + r];
                v = v > 0.f ? v : (__expf(v) - 1.f);
                x1_out[(size_t)(q0 + lg * 4 + r) * ODIM + h * DKH + fd * 16 + lr] = v;
            }
    }
}

__global__ __launch_bounds__(512) void px2_fb_k(
    const float* __restrict__ p, const short* __restrict__ qvT,
    float* __restrict__ x2_out) {
    int h = blockIdx.y;
    int k0 = blockIdx.x * 32;
    int tid = threadIdx.x, lane = tid & 63, w = tid >> 6;
    int lr = lane & 15, lg = lane >> 4;

    __shared__ float red[4][64][33];

    f32x4 acc[2][4] = {};
    const float* pbase = p + (size_t)h * NN * NN;
    const short* qvh = qvT + (size_t)h * DKH * NN;

    for (int it = 0; it < 16; it++) {
        int qq = w * 512 + it * 32;
        short8 aP[2];
#pragma unroll
        for (int fj = 0; fj < 2; fj++) {
            const float* pp = pbase + (size_t)(qq + lg * 8) * NN + k0 + fj * 16 + lr;
            short8 av;
#pragma unroll
            for (int j = 0; j < 8; j++) av[j] = f2bf(pp[j * NN]);
            aP[fj] = av;
        }
#pragma unroll
        for (int fd = 0; fd < 4; fd++) {
            short8 bv = *(const short8*)(qvh + (size_t)(fd * 16 + lr) * NN + qq + lg * 8);
#pragma unroll
            for (int fj = 0; fj < 2; fj++) acc[fj][fd] = mfma16(aP[fj], bv, acc[fj][fd]);
        }
    }
    if (w >= 4) {
#pragma unroll
        for (int fj = 0; fj < 2; fj++)
#pragma unroll
            for (int fd = 0; fd < 4; fd++)
#pragma unroll
                for (int r = 0; r < 4; r++)
                    red[w - 4][lane][fj * 16 + fd * 4 + r] = acc[fj][fd][r];
    }
    __syncthreads();
    if (w < 4) {
#pragma unroll
        for (int fj = 0; fj < 2; fj++)
#pragma unroll
            for (int fd = 0; fd < 4; fd++)
#pragma unroll
                for (int r = 0; r < 4; r++)
                    acc[fj][fd][r] += red[w][lane][fj * 16 + fd * 4 + r];
    }
    __syncthreads();
    if (w >= 1 && w < 4) {
#pragma unroll
        for (int fj = 0; fj < 2; fj++)
#pragma unroll
            for (int fd = 0; fd < 4; fd++)
#pragma unroll
                for (int r = 0; r < 4; r++)
                    red[w - 1][lane][fj * 16 + fd * 4 + r] = acc[fj][fd][r];
    }
    __syncthreads();
    if (w == 0) {
#pragma unroll
        for (int fj = 0; fj < 2; fj++)
#pragma unroll
            for (int fd = 0; fd < 4; fd++)
#pragma unroll
                for (int r = 0; r < 4; r++) {
                    float v = acc[fj][fd][r];
#pragma unroll
                    for (int s2 = 0; s2 < 3; s2++) v += red[s2][lane][fj * 16 + fd * 4 + r];
                    v = v > 0.f ? v : (__expf(v) - 1.f);
                    x2_out[(size_t)(k0 + fj * 16 + lg * 4 + r) * ODIM + h * DKH + fd * 16 + lr] = v;
                }
    }
}

extern "C" void kernel_launch(void* const* d_in, const int* in_sizes, int n_in,
                              void* d_out, int out_size, void* d_ws, size_t ws_size,
                              hipStream_t stream) {
    (void)in_sizes; (void)n_in; (void)out_size;
    const float* query = (const float*)d_in[0];
    const float* key   = (const float*)d_in[1];
    const int*   mask  = (const int*)d_in[2];
    const float* Wq  = (const float*)d_in[3];
    const float* bq  = (const float*)d_in[4];
    const float* Wk  = (const float*)d_in[5];
    const float* bk  = (const float*)d_in[6];
    const float* Wqv = (const float*)d_in[7];
    const float* bqv = (const float*)d_in[8];
    const float* Wkv = (const float*)d_in[9];
    const float* bkv = (const float*)d_in[10];

    float* out = (float*)d_out;
    float* x1 = out;
    float* x2 = out + (size_t)NN * ODIM;
    float* p  = out + (size_t)2 * NN * ODIM;

    char* ws = (char*)d_ws;
    short* qh  = (short*)(ws);
    short* kh  = (short*)(ws + (2ull << 20));
    short* qvT = (short*)(ws + (4ull << 20));
    short* kvT = (short*)(ws + (6ull << 20));
    unsigned long long* bits = (unsigned long long*)(ws + (8ull << 20));
    float* linv_ws = (float*)(ws + (10ull << 20));
    short* qvS = (short*)(ws + (10ull << 20) + (1ull << 19));
    float* x2part = (float*)(ws + (13ull << 20));            // 4 x 4 MB
    short* pbuf = (short*)(ws + (29ull << 20));               // 128 MB
    size_t need = (29ull << 20) + (size_t)NHEAD * NN * NN * sizeof(short);

    hipLaunchKernelGGL(pack_mask_k, dim3(NN * NN / 64 / 4), dim3(256), 0, stream, mask, bits);
    hipLaunchKernelGGL(proj_k, dim3(64, 4, 4), dim3(256), 0, stream,
                       query, key, Wq, bq, Wk, bk, Wqv, bqv, Wkv, bkv, qh, kh, qvT, kvT);

    if (ws_size >= need) {
        hipLaunchKernelGGL(attn_fused_k, dim3(NN / 16, NHEAD), dim3(512), 0, stream,
                           qh, kh, kvT, bits, pbuf, linv_ws, x1, p);
        hipLaunchKernelGGL(scale_qv_k, dim3(512), dim3(256), 0, stream, qvT, linv_ws, qvS);
        hipLaunchKernelGGL(px2b_k, dim3(NN / 64, NHEAD, 4), dim3(512), 0, stream,
                           pbuf, qvS, x2part);
        hipLaunchKernelGGL(combine_x2_k, dim3(NN * ODIM / 4 / 256), dim3(256), 0, stream,
                           x2part, x2);
    } else {
        hipLaunchKernelGGL(attn_fb_k, dim3(NN / 16, NHEAD), dim3(512), 0, stream,
                           qh, kh, kvT, bits, x1, p);
        hipLaunchKernelGGL(px2_fb_k, dim3(NN / 32, NHEAD), dim3(512), 0, stream,
                           p, qvT, x2);
    }
}